// Round 7
// baseline (226.094 us; speedup 1.0000x reference)
//
#include <hip/hip_runtime.h>
#include <hip/hip_bf16.h>
#include <math.h>

// Problem constants (B=2, L=1024, D=768, H=12, DH=64, LAT=512)
#define D_MODEL 768
#define NHEAD   12
#define LATD    512
#define BATCH   2
#define SEQ     1024
#define NROWS   (BATCH*SEQ)          // 2048
#define NCHUNK  (SEQ/64)             // 16
#define NBH     (BATCH*NHEAD)        // 24
#define NFUSE   3200                 // qkv 2304 + params pad 128 + gate 768
#define PQ      72                   // LDS ushort pitch (144 B rows, 16B-aligned frags)

using short8 = __attribute__((ext_vector_type(8))) short;
using f32x4  = __attribute__((ext_vector_type(4))) float;

__device__ __forceinline__ float sigf(float x){ return 1.f/(1.f+expf(-x)); }
__device__ __forceinline__ float decay_of(float hd){
  float d = 0.3f + 0.65f*sigf(hd);
  return fminf(fmaxf(d, 1e-5f), 0.999f);
}
__device__ __forceinline__ unsigned short f2b(float f){
  __hip_bfloat16 h = __float2bfloat16(f);
  return *reinterpret_cast<unsigned short*>(&h);
}
__device__ __forceinline__ float bf2f(unsigned short u){
  unsigned int x = ((unsigned int)u) << 16;
  return __uint_as_float(x);
}
__device__ __forceinline__ void async16(const unsigned short* g, unsigned short* l){
  __builtin_amdgcn_global_load_lds((const __attribute__((address_space(1))) void*)g,
                                   (__attribute__((address_space(3))) void*)l, 16, 0, 0);
}

// shared rmsnorm-row body (D=768), one block of 256 per row
__device__ __forceinline__ void rms_row(const float* __restrict__ xr,
    const float* __restrict__ w, unsigned short* __restrict__ yr,
    int tid, float* red)
{
  float v0 = xr[tid], v1 = xr[tid+256], v2 = xr[tid+512];
  float s = v0*v0 + v1*v1 + v2*v2;
  #pragma unroll
  for (int off=32; off; off>>=1) s += __shfl_xor(s, off, 64);
  if ((tid & 63) == 0) red[tid>>6] = s;
  __syncthreads();
  s = red[0]+red[1]+red[2]+red[3];
  float sc = rsqrtf(s*(1.f/(float)D_MODEL) + 1e-6f);
  yr[tid]     = f2b(v0*sc*w[tid]);
  yr[tid+256] = f2b(v1*sc*w[tid+256]);
  yr[tid+512] = f2b(v2*sc*w[tid+512]);
}

// ---------------- prep: weight converts + rmsnorm(x) + sumsq/cnt zero, ONE launch --
__global__ __launch_bounds__(256) void k_prep(
    const float* __restrict__ x, const float* __restrict__ w_ln,
    unsigned short* __restrict__ xn,
    const float* __restrict__ wc, const float* __restrict__ wq,
    const float* __restrict__ wr, const float* __restrict__ wg,
    const float* __restrict__ wp, const float* __restrict__ w_mn,
    unsigned short* __restrict__ wtc, unsigned short* __restrict__ wtq,
    unsigned short* __restrict__ wtg, unsigned short* __restrict__ wtp,
    float* __restrict__ sumsq, int* __restrict__ cnt)
{
  __shared__ unsigned short tile[64][65];
  __shared__ float red[4];
  int blk = blockIdx.x, t = threadIdx.x;
  if (blk >= 640){
    int row = blk - 640;
    rms_row(x + (size_t)row*D_MODEL, w_ln, xn + (size_t)row*D_MODEL, t, red);
    return;
  }
  const float* W; unsigned short* WT; int K, N, bx, by;
  const float* kscale = nullptr;
  if (blk < 96){ W=wc; WT=wtc; K=768; N=512; bx=blk&7; by=blk>>3; }
  else if (blk < 384){ int i=blk-96;  W=wq; WT=wtq; K=512; N=2304; bx=i%36; by=i/36; }
  else if (blk < 480){ int i=blk-384; W=wg; WT=wtg; K=512; N=768;  bx=i%12; by=i/12; }
  else if (blk < 624){ int i=blk-480; W=wp; WT=wtp; K=768; N=768;  bx=i%12; by=i/12; kscale=w_mn; }
  else {
    // w_reso [512][48] -> wtq rows 2304..2431 (zero-pad 2352..2431); blk 624 zeroes sumsq+cnt
    int i = blk - 624;                    // 0..15
    if (i == 0){
      #pragma unroll
      for (int j=0;j<8;j++) sumsq[t + j*256] = 0.f;
      if (t < 32) cnt[t] = 0;
    }
    #pragma unroll
    for (int j=0;j<16;j++){
      int e = i*4096 + t + j*256;         // 0..65535
      int n = 2304 + (e >> 9), k = e & 511;
      float v = (n < 2352) ? wr[(size_t)k*48 + (n-2304)] : 0.f;
      wtq[(size_t)n*512 + k] = f2b(v);
    }
    return;
  }
  int k0 = by*64, n0 = bx*64, cr = t >> 6, cc = t & 63;
  #pragma unroll
  for (int i=0;i<16;i++){
    int r = cr + i*4;
    float v = W[(size_t)(k0+r)*N + n0 + cc];
    if (kscale) v *= kscale[k0+r];
    tile[r][cc] = f2b(v);
  }
  __syncthreads();
  #pragma unroll
  for (int i=0;i<16;i++){
    int nn = cr + i*4;
    WT[(size_t)(n0+nn)*K + k0 + cc] = tile[cc][nn];
  }
}

// ---------------- 64x64-tile bf16 MFMA GEMM, double-buffered 2-phase pipeline ------
// act: 1 = silu (bf16 Cb); 3 = rmsnorm-scale (sums) * aux gate (fp32 Cf)
__global__ __launch_bounds__(256) void k_gemm64(const unsigned short* __restrict__ A,
    const unsigned short* __restrict__ BT, float* __restrict__ Cf,
    unsigned short* __restrict__ Cb, const unsigned short* __restrict__ auxb,
    const float* __restrict__ sums, int M, int N, int K, int act, int NX)
{
  __shared__ unsigned short As[2*64*64];   // double-buffered
  __shared__ unsigned short Bs[2*64*64];
  int tid = threadIdx.x;
  int w = tid >> 6, lane = tid & 63;
  int m16 = lane & 15, quad = lane >> 4;
  int bid = blockIdx.x, cpx = gridDim.x >> 3;
  int swz = (bid & 7)*cpx + (bid >> 3);
  int bx = swz % NX, by = swz / NX;
  int bm = by*64, bn = bx*64;

  f32x4 acc[4];
  #pragma unroll
  for (int nt=0;nt<4;nt++) acc[nt] = (f32x4){0.f,0.f,0.f,0.f};

  int nk = K >> 6;
  // prologue: stage tile 0 into buf 0
  #pragma unroll
  for (int i=0;i<2;i++){
    int g = (w*2 + i)*64 + lane;
    int m = g >> 3, c = (g & 7) ^ (m & 7);
    async16(A  + (size_t)(bm+m)*K + c*8, As + (w*2+i)*512);
    async16(BT + (size_t)(bn+m)*K + c*8, Bs + (w*2+i)*512);
  }
  __syncthreads();
  int cur = 0;
  for (int t = 0; t < nk; ++t){
    if (t+1 < nk){
      int kk = (t+1) << 6;
      int nb = cur ^ 1;
      #pragma unroll
      for (int i=0;i<2;i++){
        int g = (w*2 + i)*64 + lane;
        int m = g >> 3, c = (g & 7) ^ (m & 7);
        async16(A  + (size_t)(bm+m)*K + kk + c*8, As + nb*4096 + (w*2+i)*512);
        async16(BT + (size_t)(bn+m)*K + kk + c*8, Bs + nb*4096 + (w*2+i)*512);
      }
    }
    #pragma unroll
    for (int s=0;s<2;s++){
      int row = w*16 + m16;
      short8 af = *(const short8*)(As + cur*4096 + (row*8 + ((s*4 + quad) ^ (row & 7)))*8);
      #pragma unroll
      for (int nt=0;nt<4;nt++){
        int n = nt*16 + m16;
        short8 bf = *(const short8*)(Bs + cur*4096 + (n*8 + ((s*4 + quad) ^ (n & 7)))*8);
        acc[nt] = __builtin_amdgcn_mfma_f32_16x16x32_bf16(af, bf, acc[nt], 0, 0, 0);
      }
    }
    __syncthreads();
    cur ^= 1;
  }
  #pragma unroll
  for (int r=0;r<4;r++){
    int row = bm + w*16 + quad*4 + r;
    float rowsc = 1.f;
    if (act == 3) rowsc = rsqrtf(sums[row]*(1.f/(float)D_MODEL) + 1e-6f);
    #pragma unroll
    for (int nt=0;nt<4;nt++){
      int col = bn + nt*16 + m16;
      float v = acc[nt][r];
      if (act == 1) v = v/(1.f + __expf(-v));
      else if (act == 3) v = v*rowsc*bf2f(auxb[(size_t)row*N + col]);
      if (Cf) Cf[(size_t)row*N + col] = v;
      if (Cb) Cb[(size_t)row*N + col] = f2b(v);
    }
  }
}

// ---------------- fused GEMM: [qkv | params | gate] = latent @ BT (N=3200) ----------
// Double-buffered 2-phase pipeline; epilogue does feat (rmsnorm+rope+elu+1) + coef.
__global__ __launch_bounds__(256) void k_gemm_fused(const unsigned short* __restrict__ A,
    const unsigned short* __restrict__ BT, const float* __restrict__ w_qn,
    const float* __restrict__ w_kn, const float* __restrict__ hdec,
    const float* __restrict__ temp, unsigned short* __restrict__ qf,
    unsigned short* __restrict__ kf, unsigned short* __restrict__ vf,
    float* __restrict__ cKV, float* __restrict__ cG,
    unsigned short* __restrict__ gateb)
{
  __shared__ __align__(16) unsigned short SM[4*128*64];   // As[2] | Bs[2]; pf re-alias later
  unsigned short* As = SM;                 // [2][128*64]
  unsigned short* Bs = SM + 2*128*64;      // [2][128*64]
  const int K = LATD;
  int tid = threadIdx.x;
  int w = tid >> 6, lane = tid & 63;
  int wm = (w >> 1)*64, wn = (w & 1)*64;
  int m16 = lane & 15, quad = lane >> 4;
  int bid = blockIdx.x;
  int swz = (bid & 7)*50 + (bid >> 3);   // 400 = 8*50, bijective
  int bx = swz >> 4, by = swz & 15;      // by fastest within an XCD chunk
  int bm = by*128, bn = bx*128;

  f32x4 acc[4][4];
  #pragma unroll
  for (int i=0;i<4;i++)
    #pragma unroll
    for (int j=0;j<4;j++) acc[i][j] = (f32x4){0.f,0.f,0.f,0.f};

  const int nk = K >> 6;                 // 8
  // prologue: stage tile 0 into buf 0
  #pragma unroll
  for (int i=0;i<4;i++){
    int g = (w*4 + i)*64 + lane;
    int m = g >> 3, c = (g & 7) ^ (m & 7);
    async16(A  + (size_t)(bm+m)*K + c*8, As + (w*4+i)*512);
    async16(BT + (size_t)(bn+m)*K + c*8, Bs + (w*4+i)*512);
  }
  __syncthreads();
  int cur = 0;
  for (int t = 0; t < nk; ++t){
    if (t+1 < nk){
      int kk = (t+1) << 6;
      int nb = cur ^ 1;
      #pragma unroll
      for (int i=0;i<4;i++){
        int g = (w*4 + i)*64 + lane;
        int m = g >> 3, c = (g & 7) ^ (m & 7);
        async16(A  + (size_t)(bm+m)*K + kk + c*8, As + nb*8192 + (w*4+i)*512);
        async16(BT + (size_t)(bn+m)*K + kk + c*8, Bs + nb*8192 + (w*4+i)*512);
      }
    }
    #pragma unroll
    for (int s=0;s<2;s++){
      short8 af[4], bf[4];
      #pragma unroll
      for (int mt=0;mt<4;mt++){
        int m = wm + mt*16 + m16;
        int idx = m*8 + ((s*4 + quad) ^ (m & 7));
        af[mt] = *(const short8*)(As + cur*8192 + idx*8);
      }
      #pragma unroll
      for (int nt=0;nt<4;nt++){
        int n = wn + nt*16 + m16;
        int idx = n*8 + ((s*4 + quad) ^ (n & 7));
        bf[nt] = *(const short8*)(Bs + cur*8192 + idx*8);
      }
      #pragma unroll
      for (int mt=0;mt<4;mt++)
        #pragma unroll
        for (int nt=0;nt<4;nt++)
          acc[mt][nt] = __builtin_amdgcn_mfma_f32_16x16x32_bf16(af[mt], bf[nt], acc[mt][nt], 0, 0, 0);
    }
    __syncthreads();
    cur ^= 1;
  }

  int colbase = bn + wn;                // 64-aligned; wave owns cols [colbase, colbase+64)
  if (colbase < 2304){
    int sec = colbase >= 1536 ? 2 : (colbase >= 768 ? 1 : 0);   // 0=q 1=k 2=v
    int h = (colbase - sec*768) >> 6;
    if (sec == 2){
      #pragma unroll
      for (int mt=0;mt<4;mt++)
        #pragma unroll
        for (int r=0;r<4;r++){
          int row = bm + wm + mt*16 + quad*4 + r;
          int b = row >> 10, t = row & 1023;
          size_t ob = (((size_t)(b*NHEAD+h))*SEQ + t)*64;
          #pragma unroll
          for (int nt=0;nt<4;nt++)
            vf[ob + nt*16 + m16] = f2b(acc[mt][nt][r]);
        }
    } else {
      const float* wnp = sec ? w_kn : w_qn;
      unsigned short* of = sec ? kf : qf;
      float wv4[4];
      #pragma unroll
      for (int nt=0;nt<4;nt++) wv4[nt] = wnp[nt*16 + m16];
      float inv0 = exp2f(-(float)m16*(1.f/32.f)*13.28771237954945f);  // 10000^{-m16/32}
      float inv1 = inv0 * 0.01f;                                      // * 10000^{-16/32}
      #pragma unroll
      for (int mt=0;mt<4;mt++)
        #pragma unroll
        for (int r=0;r<4;r++){
          int row = bm + wm + mt*16 + quad*4 + r;
          int b = row >> 10, t = row & 1023;
          float s = 0.f;
          #pragma unroll
          for (int nt=0;nt<4;nt++) s += acc[mt][nt][r]*acc[mt][nt][r];
          s += __shfl_xor(s, 1, 64); s += __shfl_xor(s, 2, 64);
          s += __shfl_xor(s, 4, 64); s += __shfl_xor(s, 8, 64);
          float rs = rsqrtf(s*(1.f/64.f) + 1e-6f);
          float qv[4];
          #pragma unroll
          for (int nt=0;nt<4;nt++) qv[nt] = acc[mt][nt][r]*rs*wv4[nt];
          float s0,c0,s1,c1;
          __sincosf((float)t*inv0, &s0, &c0);
          __sincosf((float)t*inv1, &s1, &c1);
          size_t ob = (((size_t)(b*NHEAD+h))*SEQ + t)*64;
          #pragma unroll
          for (int nt=0;nt<4;nt++){
            float rot = (nt < 2) ? -qv[nt+2] : qv[nt-2];
            float cs = (nt & 1) ? c1 : c0, sn = (nt & 1) ? s1 : s0;
            float val = qv[nt]*cs + rot*sn;
            val = (val > 0.f) ? val + 1.f : __expf(val);
            of[ob + nt*16 + m16] = f2b(val);
          }
        }
    }
  } else if (colbase < 2432){
    // resonance params block: all 4 waves of this block land here -> block sync OK.
    float* pf = (float*)SM;               // [128][49] fp32 = 25088 B
    if (colbase == 2304){
      #pragma unroll
      for (int mt=0;mt<4;mt++)
        #pragma unroll
        for (int r=0;r<4;r++){
          int rowl = wm + mt*16 + quad*4 + r;
          #pragma unroll
          for (int nt=0;nt<4;nt++){
            int p = nt*16 + m16;
            if (p < 48) pf[rowl*49 + p] = acc[mt][nt][r];
          }
        }
    }
    __syncthreads();
    float tv = temp[0];
    #pragma unroll
    for (int i=0;i<6;i++){
      int idx2 = tid + i*256;             // 0..1535 = 128 rows x 12 heads
      int rowl = idx2 / 12, h = idx2 - rowl*12;
      int row = bm + rowl, b = row >> 10, t = row & 1023;
      const float* pr = pf + rowl*49 + h*4;
      float sa = sigf(pr[0]);
      float sp = sigf(pr[1])*3.14159265358979323846f;
      float ca = sigf(pr[2]);
      float cp = sigf(pr[3])*3.14159265358979323846f;
      float z = sa*ca*cosf(sp - cp)*tv;
      float gate = fminf(fmaxf(sigf(z)*1.2f - 0.1f, 0.05f), 0.95f);
      float dd = decay_of(hdec[h]);
      float df = expf((float)(t+1)*logf(dd));
      float g = df/(df + 1e-8f);
      int ci = (b*NHEAD + h)*SEQ + t;
      cKV[ci] = g*gate*(1.f - dd);
      cG[ci]  = 1.f/gate;
    }
  } else {
    // out-gate: silu -> bf16
    #pragma unroll
    for (int mt=0;mt<4;mt++)
      #pragma unroll
      for (int r=0;r<4;r++){
        int row = bm + wm + mt*16 + quad*4 + r;
        #pragma unroll
        for (int nt=0;nt<4;nt++){
          int gc = colbase + nt*16 + m16 - 2432;
          float v = acc[mt][nt][r];
          v = v/(1.f + __expf(-v));
          gateb[(size_t)row*D_MODEL + gc] = f2b(v);
        }
      }
  }
}

// ---------------- fused attention core: intra + flag-synced cross (one launch) -----
// Block (bh,chunk): intra phase computes scores/num/den (num/den stay in REGISTERS),
// writes P/zP, publishes via release fence + per-bh counter. Cross phase waits for
// all 16 intras of its bh (all 384 blocks co-resident: 49KB LDS -> 3 blocks/CU,
// capacity 768 >= 384), then prefix-combines P in-register and finishes in LDS-
// resident Q. XCD swizzle keeps same-bh blocks on one XCD for P L2 locality.
__global__ __launch_bounds__(256) void k_attn(const unsigned short* __restrict__ qf,
    const unsigned short* __restrict__ kf, const unsigned short* __restrict__ vf,
    const float* __restrict__ cKVb, const float* __restrict__ cGb,
    const float* __restrict__ hdec, float* __restrict__ Pb, float* __restrict__ zPb,
    int* __restrict__ cnt, unsigned short* __restrict__ attnb,
    float* __restrict__ sumsq)
{
  __shared__ __align__(16) unsigned short Qb[64*PQ];   // Q_f  [t][k] — persists to cross
  __shared__ __align__(16) unsigned short Kb[64*PQ];   // K_f  [s][d]
  __shared__ __align__(16) unsigned short KtS[64*PQ];  // (K_f*cps)^T [d][s]
  __shared__ __align__(16) unsigned short Wb[64*PQ];   // Wn   [t][s]
  __shared__ __align__(16) unsigned short Vt[80*PQ];   // V^T (intra) | S_prev (cross)
  __shared__ float cn[64], cps[64], den_sm[64];
  int bid = blockIdx.x;
  int swz = (bid & 7)*48 + (bid >> 3);     // 384 = 8*48, bijective
  int chunk = swz & 15, bh = swz >> 4;
  int h = bh % NHEAD, b = bh / NHEAD;
  int tid = threadIdx.x, w = tid >> 6, lane = tid & 63;
  int m16 = lane & 15, quad = lane >> 4;
  int trow = w*16 + quad*4;
  size_t base = ((size_t)bh*SEQ + chunk*64)*64;
  float d = decay_of(hdec[h]);
  float l2d = log2f(d);
  float d64l2 = 64.f*l2d;

  // ======== phase 1: intra-chunk ========
  if (tid < 64){
    float c = cKVb[bh*SEQ + chunk*64 + tid];
    float pw = exp2f((float)(63 - tid)*l2d);
    cn[tid] = c;
    cps[tid] = c*pw;
    Vt[64*PQ + tid] = f2b(cGb[bh*SEQ + chunk*64 + tid]);
  }
  for (int i = tid; i < 15*PQ; i += 256) Vt[65*PQ + i] = 0;
  __syncthreads();   // cps ready for KtS staging

  #pragma unroll
  for (int i=0;i<2;i++){
    int g = tid + i*256;
    int r = g >> 3, c8 = (g & 7)*8;
    *(short8*)(Qb + r*PQ + c8) = *(const short8*)(qf + base + r*64 + c8);
    *(short8*)(Kb + r*PQ + c8) = *(const short8*)(kf + base + r*64 + c8);
  }
  {
    int s = tid & 63;
    float cpss = cps[s];
    #pragma unroll
    for (int i=0;i<2;i++){
      int c8 = ((tid >> 6) + i*4)*8;
      short8 vv = *(const short8*)(vf + base + s*64 + c8);
      short8 kk = *(const short8*)(kf + base + s*64 + c8);
      #pragma unroll
      for (int j=0;j<8;j++){
        Vt[(c8+j)*PQ + s] = ((unsigned short*)&vv)[j];
        KtS[(c8+j)*PQ + s] = f2b(bf2f(((unsigned short*)&kk)[j])*cpss);
      }
    }
  }
  __syncthreads();

  for (int stile=0; stile<4; stile++){
    if (stile > w){
      #pragma unroll
      for (int r=0;r<4;r++) Wb[(trow+r)*PQ + stile*16 + m16] = 0;
      continue;
    }
    f32x4 acc = (f32x4){0.f,0.f,0.f,0.f};
    #pragma unroll
    for (int ks=0;ks<2;ks++){
      short8 a = *(const short8*)(Qb + (w*16 + m16)*PQ + ks*32 + quad*8);
      short8 bb = *(const short8*)(Kb + (stile*16 + m16)*PQ + ks*32 + quad*8);
      acc = __builtin_amdgcn_mfma_f32_16x16x32_bf16(a, bb, acc, 0, 0, 0);
    }
    int s = stile*16 + m16;
    float cns = cn[s];
    #pragma unroll
    for (int r=0;r<4;r++){
      int t = trow + r;
      float wv = 0.f;
      if (s <= t) wv = acc[r]*exp2f((float)(t-s)*l2d)*cns;
      Wb[t*PQ + s] = f2b(wv);
    }
  }
  __syncthreads();

  // num/den accumulators — stay in registers through the cross phase
  f32x4 accN[5];
  #pragma unroll
  for (int et=0;et<5;et++) accN[et] = (f32x4){0.f,0.f,0.f,0.f};
  #pragma unroll
  for (int et=0;et<5;et++)
    #pragma unroll
    for (int ks=0;ks<2;ks++){
      short8 a = *(const short8*)(Wb + (w*16 + m16)*PQ + ks*32 + quad*8);
      short8 bb = *(const short8*)(Vt + (et*16 + m16)*PQ + ks*32 + quad*8);
      accN[et] = __builtin_amdgcn_mfma_f32_16x16x32_bf16(a, bb, accN[et], 0, 0, 0);
    }

  // P^T / zP to global for the prefix combine
  {
    #pragma unroll
    for (int j=0;j<5;j++){
      int tIdx = w + 4*j;
      int et = tIdx >> 2, dt = tIdx & 3;
      f32x4 acc = (f32x4){0.f,0.f,0.f,0.f};
      #pragma unroll
      for (int ks=0;ks<2;ks++){
        short8 a = *(const short8*)(Vt  + (et*16 + m16)*PQ + ks*32 + quad*8);
        short8 bb = *(const short8*)(KtS + (dt*16 + m16)*PQ + ks*32 + quad*8);
        acc = __builtin_amdgcn_mfma_f32_16x16x32_bf16(a, bb, acc, 0, 0, 0);
      }
      if (et < 4){
        #pragma unroll
        for (int r=0;r<4;r++)
          Pb[((size_t)(bh*NCHUNK + chunk))*4096 + (et*16 + quad*4 + r)*64 + dt*16 + m16] = acc[r];
      } else {
        if (quad == 0) zPb[(bh*NCHUNK + chunk)*64 + dt*16 + m16] = acc[0];
      }
    }
  }

  // ======== publish (release) and wait (acquire) ========
  __syncthreads();                 // drain all P/zP stores (compiler emits vmcnt(0))
  __threadfence();                 // device-scope release: L2 writeback
  if (tid == 0) atomicAdd(&cnt[bh], 1);
  if (chunk > 0){
    if (tid == 0){
      while (__hip_atomic_load(&cnt[bh], __ATOMIC_RELAXED, __HIP_MEMORY_SCOPE_AGENT) < NCHUNK)
        __builtin_amdgcn_s_sleep(2);
    }
    __syncthreads();
    __threadfence();               // device-scope acquire: invalidate stale caches
  }

  // ======== phase 2: cross-chunk combine (Qb resident, num/den in registers) =======
  // prefix-combine P -> S_prev into Vt (rows 0..63), zprev into row 64
  {
    int r = tid >> 3, c8 = (tid & 7)*8;    // rows r and r+32, cols c8..c8+7
    float a0[8], a1[8];
    #pragma unroll
    for (int j=0;j<8;j++){ a0[j]=0.f; a1[j]=0.f; }
    for (int c=0;c<chunk;c++){
      float wgt = exp2f((float)(chunk-1-c)*d64l2);
      const float* ps = Pb + ((size_t)(bh*NCHUNK + c))*4096;
      float4 p0 = *(const float4*)(ps + r*64 + c8);
      float4 p1 = *(const float4*)(ps + r*64 + c8 + 4);
      float4 p2 = *(const float4*)(ps + (r+32)*64 + c8);
      float4 p3 = *(const float4*)(ps + (r+32)*64 + c8 + 4);
      a0[0]+=wgt*p0.x; a0[1]+=wgt*p0.y; a0[2]+=wgt*p0.z; a0[3]+=wgt*p0.w;
      a0[4]+=wgt*p1.x; a0[5]+=wgt*p1.y; a0[6]+=wgt*p1.z; a0[7]+=wgt*p1.w;
      a1[0]+=wgt*p2.x; a1[1]+=wgt*p2.y; a1[2]+=wgt*p2.z; a1[3]+=wgt*p2.w;
      a1[4]+=wgt*p3.x; a1[5]+=wgt*p3.y; a1[6]+=wgt*p3.z; a1[7]+=wgt*p3.w;
    }
    #pragma unroll
    for (int j=0;j<8;j++){
      Vt[r*PQ + c8 + j]      = f2b(a0[j]);
      Vt[(r+32)*PQ + c8 + j] = f2b(a1[j]);
    }
  }
  if (tid < 64){
    float z = 0.f;
    for (int c=0;c<chunk;c++)
      z += exp2f((float)(chunk-1-c)*d64l2) * zPb[(bh*NCHUNK + c)*64 + tid];
    Vt[64*PQ + tid] = f2b(z);
  }
  // Vt rows 65..79 still zero from phase 1
  __syncthreads();

  f32x4 acc2[5];
  #pragma unroll
  for (int et=0;et<5;et++) acc2[et] = (f32x4){0.f,0.f,0.f,0.f};
  #pragma unroll
  for (int et=0;et<5;et++)
    #pragma unroll
    for (int ks=0;ks<2;ks++){
      short8 a = *(const short8*)(Qb + (w*16 + m16)*PQ + ks*32 + quad*8);
      short8 bb = *(const short8*)(Vt + (et*16 + m16)*PQ + ks*32 + quad*8);
      acc2[et] = __builtin_amdgcn_mfma_f32_16x16x32_bf16(a, bb, acc2[et], 0, 0, 0);
    }
  if (m16 == 0){
    #pragma unroll
    for (int r=0;r<4;r++){
      int tl = trow + r;
      float pw = exp2f((float)(tl+1)*l2d);
      float den = fmaxf(accN[4][r] + pw*acc2[4][r], 1e-5f);
      den_sm[tl] = 1.f/den;
    }
  }
  __syncthreads();
  #pragma unroll
  for (int r=0;r<4;r++){
    int tl = trow + r;
    float pw = exp2f((float)(tl+1)*l2d);
    float invden = den_sm[tl];
    int rowg = b*SEQ + chunk*64 + tl;
    float ls = 0.f;
    #pragma unroll
    for (int et=0;et<4;et++){
      int e = et*16 + m16;
      float ov = (accN[et][r] + pw*acc2[et][r])*invden;
      attnb[(size_t)rowg*D_MODEL + h*64 + e] = f2b(ov);
      ls += ov*ov;
    }
    ls += __shfl_xor(ls, 1, 64); ls += __shfl_xor(ls, 2, 64);
    ls += __shfl_xor(ls, 4, 64); ls += __shfl_xor(ls, 8, 64);
    if (m16 == 0) atomicAdd(&sumsq[rowg], ls);
  }
}

extern "C" void kernel_launch(void* const* d_in, const int* in_sizes, int n_in,
                              void* d_out, int out_size, void* d_ws, size_t ws_size,
                              hipStream_t stream)
{
  (void)in_sizes; (void)n_in; (void)out_size; (void)ws_size;
  const float* x       = (const float*)d_in[0];
  const float* w_ln    = (const float*)d_in[1];
  const float* w_comp  = (const float*)d_in[2];
  const float* w_qkv   = (const float*)d_in[3];
  const float* w_reso  = (const float*)d_in[4];
  const float* w_qn    = (const float*)d_in[5];
  const float* w_kn    = (const float*)d_in[6];
  const float* hdec    = (const float*)d_in[7];
  const float* temp    = (const float*)d_in[8];
  const float* w_ogate = (const float*)d_in[9];
  const float* w_proj  = (const float*)d_in[10];
  const float* w_mn    = (const float*)d_in[11];
  float* ws = (float*)d_ws;
  float* out = (float*)d_out;

  // fp32 region (floats)
  const size_t o_cKV    = 0;
  const size_t o_cG     = o_cKV    + (size_t)NBH*SEQ;
  const size_t o_P      = o_cG     + (size_t)NBH*SEQ;          // 24*16*4096 ([e][d])
  const size_t o_zP     = o_P      + (size_t)NBH*NCHUNK*4096;
  const size_t o_sumsq  = o_zP     + (size_t)NBH*NCHUNK*64;    // 2048 floats
  const size_t o_cnt    = o_sumsq  + (size_t)NROWS;            // 32 int slots
  const size_t o_end    = o_cnt    + 32;

  // bf16 region (ushorts)
  unsigned short* bws = (unsigned short*)(ws + o_end);
  const size_t u_xn     = 0;
  const size_t u_latent = u_xn     + (size_t)NROWS*D_MODEL;
  const size_t u_memn   = u_latent + (size_t)NROWS*LATD;       // bf16 attn (A of out-GEMM)
  const size_t u_q      = u_memn   + (size_t)NROWS*D_MODEL;
  const size_t u_k      = u_q      + (size_t)NBH*SEQ*64;
  const size_t u_v      = u_k      + (size_t)NBH*SEQ*64;
  const size_t u_gate   = u_v      + (size_t)NBH*SEQ*64;       // 2048*768
  const size_t u_wtc    = u_gate   + (size_t)NROWS*D_MODEL;
  const size_t u_wtq    = u_wtc    + (size_t)LATD*D_MODEL;     // 2432*512, wtg follows
  const size_t u_wtg    = u_wtq    + (size_t)2432*LATD;        // contiguous: fused BT rows 2432..3199
  const size_t u_wtp    = u_wtg    + (size_t)D_MODEL*LATD;     // w_proj^T with w_mn folded

  // 1. weight converts (w_mn folded into wtp) + rmsnorm(x) + sumsq/cnt zero
  k_prep<<<2688, 256, 0, stream>>>(x, w_ln, bws + u_xn,
      w_comp, w_qkv, w_reso, w_ogate, w_proj, w_mn,
      bws + u_wtc, bws + u_wtq, bws + u_wtg, bws + u_wtp,
      ws + o_sumsq, (int*)(ws + o_cnt));
  // 2. latent = silu(xn @ w_compress) -> bf16   (64x64 tiles, 256 blocks, pipelined)
  k_gemm64<<<256, 256, 0, stream>>>(bws + u_xn, bws + u_wtc,
      nullptr, bws + u_latent, nullptr, nullptr, NROWS, LATD, D_MODEL, 1, LATD/64);
  // 3. fused qkv+params+gate GEMM with feat + coef epilogue (400 blocks, pipelined)
  k_gemm_fused<<<400, 256, 0, stream>>>(bws + u_latent, bws + u_wtq,
      w_qn, w_kn, hdec, temp, bws + u_q, bws + u_k, bws + u_v,
      ws + o_cKV, ws + o_cG, bws + u_gate);
  // 4. fused attention core: intra + flag-synced cross (384 blocks, one launch)
  k_attn<<<NBH*NCHUNK, 256, 0, stream>>>(bws + u_q, bws + u_k, bws + u_v,
      ws + o_cKV, ws + o_cG, hdec, ws + o_P, ws + o_zP,
      (int*)(ws + o_cnt), bws + u_memn, ws + o_sumsq);
  // 5. out = rmsnorm-scale * (attn_bf16 @ wtp') * gate  (384 blocks, pipelined)
  k_gemm64<<<384, 256, 0, stream>>>(bws + u_memn, bws + u_wtp,
      out, nullptr, bws + u_gate, ws + o_sumsq, NROWS, D_MODEL, D_MODEL, 3, D_MODEL/64);
}

// Round 8
// 156.730 us; speedup vs baseline: 1.4426x; 1.4426x over previous
//
#include <hip/hip_runtime.h>
#include <hip/hip_bf16.h>
#include <math.h>

// Problem constants (B=2, L=1024, D=768, H=12, DH=64, LAT=512)
#define D_MODEL 768
#define NHEAD   12
#define LATD    512
#define BATCH   2
#define SEQ     1024
#define NROWS   (BATCH*SEQ)          // 2048
#define NCHUNK  (SEQ/64)             // 16
#define NBH     (BATCH*NHEAD)        // 24
#define NFUSE   3136                 // qkv 2304 + params pad 64 + gate 768
#define PQ      72                   // LDS ushort pitch (144 B rows, 16B-aligned frags)

using short8 = __attribute__((ext_vector_type(8))) short;
using f32x4  = __attribute__((ext_vector_type(4))) float;

__device__ __forceinline__ float sigf(float x){ return 1.f/(1.f+expf(-x)); }
__device__ __forceinline__ float decay_of(float hd){
  float d = 0.3f + 0.65f*sigf(hd);
  return fminf(fmaxf(d, 1e-5f), 0.999f);
}
__device__ __forceinline__ unsigned short f2b(float f){
  __hip_bfloat16 h = __float2bfloat16(f);
  return *reinterpret_cast<unsigned short*>(&h);
}
__device__ __forceinline__ float bf2f(unsigned short u){
  unsigned int x = ((unsigned int)u) << 16;
  return __uint_as_float(x);
}
__device__ __forceinline__ void async16(const unsigned short* g, unsigned short* l){
  __builtin_amdgcn_global_load_lds((const __attribute__((address_space(1))) void*)g,
                                   (__attribute__((address_space(3))) void*)l, 16, 0, 0);
}

// shared rmsnorm-row body (D=768), one block of 256 per row
__device__ __forceinline__ void rms_row(const float* __restrict__ xr,
    const float* __restrict__ w, unsigned short* __restrict__ yr,
    int tid, float* red)
{
  float v0 = xr[tid], v1 = xr[tid+256], v2 = xr[tid+512];
  float s = v0*v0 + v1*v1 + v2*v2;
  #pragma unroll
  for (int off=32; off; off>>=1) s += __shfl_xor(s, off, 64);
  if ((tid & 63) == 0) red[tid>>6] = s;
  __syncthreads();
  s = red[0]+red[1]+red[2]+red[3];
  float sc = rsqrtf(s*(1.f/(float)D_MODEL) + 1e-6f);
  yr[tid]     = f2b(v0*sc*w[tid]);
  yr[tid+256] = f2b(v1*sc*w[tid+256]);
  yr[tid+512] = f2b(v2*sc*w[tid+512]);
}

// ---------------- prep: weight converts + rmsnorm(x) + sumsq zero, ONE launch ------
__global__ __launch_bounds__(256) void k_prep(
    const float* __restrict__ x, const float* __restrict__ w_ln,
    unsigned short* __restrict__ xn,
    const float* __restrict__ wc, const float* __restrict__ wq,
    const float* __restrict__ wr, const float* __restrict__ wg,
    const float* __restrict__ wp, const float* __restrict__ w_mn,
    unsigned short* __restrict__ wtc, unsigned short* __restrict__ wtq,
    unsigned short* __restrict__ wtg, unsigned short* __restrict__ wtp,
    float* __restrict__ sumsq)
{
  __shared__ unsigned short tile[64][65];
  __shared__ float red[4];
  int blk = blockIdx.x, t = threadIdx.x;
  if (blk >= 640){
    int row = blk - 640;
    rms_row(x + (size_t)row*D_MODEL, w_ln, xn + (size_t)row*D_MODEL, t, red);
    return;
  }
  const float* W; unsigned short* WT; int K, N, bx, by;
  const float* kscale = nullptr;
  if (blk < 96){ W=wc; WT=wtc; K=768; N=512; bx=blk&7; by=blk>>3; }
  else if (blk < 384){ int i=blk-96;  W=wq; WT=wtq; K=512; N=2304; bx=i%36; by=i/36; }
  else if (blk < 480){ int i=blk-384; W=wg; WT=wtg; K=512; N=768;  bx=i%12; by=i/12; }
  else if (blk < 624){ int i=blk-480; W=wp; WT=wtp; K=768; N=768;  bx=i%12; by=i/12; kscale=w_mn; }
  else {
    // w_reso [512][48] -> wtq rows 2304..2367 (zero-pad 2352..2367); blk 624 zeroes sumsq
    int i = blk - 624;                    // 0..15
    if (i == 0){
      #pragma unroll
      for (int j=0;j<8;j++) sumsq[t + j*256] = 0.f;
    }
    #pragma unroll
    for (int j=0;j<8;j++){
      int e = i*2048 + t + j*256;         // 0..32767 = 64 rows x 512
      int n = 2304 + (e >> 9), k = e & 511;
      float v = (n < 2352) ? wr[(size_t)k*48 + (n-2304)] : 0.f;
      wtq[(size_t)n*512 + k] = f2b(v);
    }
    return;
  }
  int k0 = by*64, n0 = bx*64, cr = t >> 6, cc = t & 63;
  #pragma unroll
  for (int i=0;i<16;i++){
    int r = cr + i*4;
    float v = W[(size_t)(k0+r)*N + n0 + cc];
    if (kscale) v *= kscale[k0+r];
    tile[r][cc] = f2b(v);
  }
  __syncthreads();
  #pragma unroll
  for (int i=0;i<16;i++){
    int nn = cr + i*4;
    WT[(size_t)(n0+nn)*K + k0 + cc] = tile[cc][nn];
  }
}

// ---------------- 64x64-tile bf16 MFMA GEMM, double-buffered 2-phase pipeline ------
// act: 1 = silu (bf16 Cb); 3 = rmsnorm-scale (sums) * aux gate (fp32 Cf)
__global__ __launch_bounds__(256) void k_gemm64(const unsigned short* __restrict__ A,
    const unsigned short* __restrict__ BT, float* __restrict__ Cf,
    unsigned short* __restrict__ Cb, const unsigned short* __restrict__ auxb,
    const float* __restrict__ sums, int M, int N, int K, int act, int NX)
{
  __shared__ unsigned short As[2*64*64];   // double-buffered
  __shared__ unsigned short Bs[2*64*64];
  int tid = threadIdx.x;
  int w = tid >> 6, lane = tid & 63;
  int m16 = lane & 15, quad = lane >> 4;
  int bid = blockIdx.x, cpx = gridDim.x >> 3;
  int swz = (bid & 7)*cpx + (bid >> 3);
  int bx = swz % NX, by = swz / NX;
  int bm = by*64, bn = bx*64;

  f32x4 acc[4];
  #pragma unroll
  for (int nt=0;nt<4;nt++) acc[nt] = (f32x4){0.f,0.f,0.f,0.f};

  int nk = K >> 6;
  #pragma unroll
  for (int i=0;i<2;i++){
    int g = (w*2 + i)*64 + lane;
    int m = g >> 3, c = (g & 7) ^ (m & 7);
    async16(A  + (size_t)(bm+m)*K + c*8, As + (w*2+i)*512);
    async16(BT + (size_t)(bn+m)*K + c*8, Bs + (w*2+i)*512);
  }
  __syncthreads();
  int cur = 0;
  for (int t = 0; t < nk; ++t){
    if (t+1 < nk){
      int kk = (t+1) << 6;
      int nb = cur ^ 1;
      #pragma unroll
      for (int i=0;i<2;i++){
        int g = (w*2 + i)*64 + lane;
        int m = g >> 3, c = (g & 7) ^ (m & 7);
        async16(A  + (size_t)(bm+m)*K + kk + c*8, As + nb*4096 + (w*2+i)*512);
        async16(BT + (size_t)(bn+m)*K + kk + c*8, Bs + nb*4096 + (w*2+i)*512);
      }
    }
    #pragma unroll
    for (int s=0;s<2;s++){
      int row = w*16 + m16;
      short8 af = *(const short8*)(As + cur*4096 + (row*8 + ((s*4 + quad) ^ (row & 7)))*8);
      #pragma unroll
      for (int nt=0;nt<4;nt++){
        int n = nt*16 + m16;
        short8 bf = *(const short8*)(Bs + cur*4096 + (n*8 + ((s*4 + quad) ^ (n & 7)))*8);
        acc[nt] = __builtin_amdgcn_mfma_f32_16x16x32_bf16(af, bf, acc[nt], 0, 0, 0);
      }
    }
    __syncthreads();
    cur ^= 1;
  }
  #pragma unroll
  for (int r=0;r<4;r++){
    int row = bm + w*16 + quad*4 + r;
    float rowsc = 1.f;
    if (act == 3) rowsc = rsqrtf(sums[row]*(1.f/(float)D_MODEL) + 1e-6f);
    #pragma unroll
    for (int nt=0;nt<4;nt++){
      int col = bn + nt*16 + m16;
      float v = acc[nt][r];
      if (act == 1) v = v/(1.f + __expf(-v));
      else if (act == 3) v = v*rowsc*bf2f(auxb[(size_t)row*N + col]);
      if (Cf) Cf[(size_t)row*N + col] = v;
      if (Cb) Cb[(size_t)row*N + col] = f2b(v);
    }
  }
}

// ---------------- fused GEMM, 64x64 tiles: [qkv | params | gate] = latent @ BT ------
// N = 3136 (qkv 2304 | params 2304..2367 | gate 2368..3135). Grid 49x32 = 1568 blocks.
// Epilogue: per-head rmsnorm+rope+elu+1 (q/k), v passthrough, coef (cKV/cG), silu gate.
__global__ __launch_bounds__(256) void k_gemm_fused64(const unsigned short* __restrict__ A,
    const unsigned short* __restrict__ BT, const float* __restrict__ w_qn,
    const float* __restrict__ w_kn, const float* __restrict__ hdec,
    const float* __restrict__ temp, unsigned short* __restrict__ qf,
    unsigned short* __restrict__ kf, unsigned short* __restrict__ vf,
    float* __restrict__ cKV, float* __restrict__ cG,
    unsigned short* __restrict__ gateb)
{
  __shared__ __align__(16) unsigned short As[2*64*64];   // re-aliased as fp32 pf in params
  __shared__ __align__(16) unsigned short Bs[2*64*64];
  const int K = LATD;
  int tid = threadIdx.x;
  int w = tid >> 6, lane = tid & 63;
  int m16 = lane & 15, quad = lane >> 4;
  int bid = blockIdx.x, cpx = gridDim.x >> 3;   // 1568/8 = 196
  int swz = (bid & 7)*cpx + (bid >> 3);
  int bx = swz % 49, by = swz / 49;
  int bm = by*64, bn = bx*64;

  f32x4 acc[4];
  #pragma unroll
  for (int nt=0;nt<4;nt++) acc[nt] = (f32x4){0.f,0.f,0.f,0.f};

  const int nk = K >> 6;                 // 8
  #pragma unroll
  for (int i=0;i<2;i++){
    int g = (w*2 + i)*64 + lane;
    int m = g >> 3, c = (g & 7) ^ (m & 7);
    async16(A  + (size_t)(bm+m)*K + c*8, As + (w*2+i)*512);
    async16(BT + (size_t)(bn+m)*K + c*8, Bs + (w*2+i)*512);
  }
  __syncthreads();
  int cur = 0;
  for (int t = 0; t < nk; ++t){
    if (t+1 < nk){
      int kk = (t+1) << 6;
      int nb = cur ^ 1;
      #pragma unroll
      for (int i=0;i<2;i++){
        int g = (w*2 + i)*64 + lane;
        int m = g >> 3, c = (g & 7) ^ (m & 7);
        async16(A  + (size_t)(bm+m)*K + kk + c*8, As + nb*4096 + (w*2+i)*512);
        async16(BT + (size_t)(bn+m)*K + kk + c*8, Bs + nb*4096 + (w*2+i)*512);
      }
    }
    #pragma unroll
    for (int s=0;s<2;s++){
      int row = w*16 + m16;
      short8 af = *(const short8*)(As + cur*4096 + (row*8 + ((s*4 + quad) ^ (row & 7)))*8);
      #pragma unroll
      for (int nt=0;nt<4;nt++){
        int n = nt*16 + m16;
        short8 bf = *(const short8*)(Bs + cur*4096 + (n*8 + ((s*4 + quad) ^ (n & 7)))*8);
        acc[nt] = __builtin_amdgcn_mfma_f32_16x16x32_bf16(af, bf, acc[nt], 0, 0, 0);
      }
    }
    __syncthreads();
    cur ^= 1;
  }

  int colbase = bn;                      // block owns cols [colbase, colbase+64)
  if (colbase < 2304){
    int sec = colbase >= 1536 ? 2 : (colbase >= 768 ? 1 : 0);   // 0=q 1=k 2=v
    int h = (colbase - sec*768) >> 6;
    if (sec == 2){
      #pragma unroll
      for (int r=0;r<4;r++){
        int row = bm + w*16 + quad*4 + r;
        int b = row >> 10, t = row & 1023;
        size_t ob = (((size_t)(b*NHEAD+h))*SEQ + t)*64;
        #pragma unroll
        for (int nt=0;nt<4;nt++)
          vf[ob + nt*16 + m16] = f2b(acc[nt][r]);
      }
    } else {
      const float* wnp = sec ? w_kn : w_qn;
      unsigned short* of = sec ? kf : qf;
      float wv4[4];
      #pragma unroll
      for (int nt=0;nt<4;nt++) wv4[nt] = wnp[nt*16 + m16];
      float inv0 = exp2f(-(float)m16*(1.f/32.f)*13.28771237954945f);  // 10000^{-m16/32}
      float inv1 = inv0 * 0.01f;                                      // * 10000^{-16/32}
      #pragma unroll
      for (int r=0;r<4;r++){
        int row = bm + w*16 + quad*4 + r;
        int b = row >> 10, t = row & 1023;
        float s = 0.f;
        #pragma unroll
        for (int nt=0;nt<4;nt++) s += acc[nt][r]*acc[nt][r];
        s += __shfl_xor(s, 1, 64); s += __shfl_xor(s, 2, 64);
        s += __shfl_xor(s, 4, 64); s += __shfl_xor(s, 8, 64);
        float rs = rsqrtf(s*(1.f/64.f) + 1e-6f);
        float qv[4];
        #pragma unroll
        for (int nt=0;nt<4;nt++) qv[nt] = acc[nt][r]*rs*wv4[nt];
        float s0,c0,s1,c1;
        __sincosf((float)t*inv0, &s0, &c0);
        __sincosf((float)t*inv1, &s1, &c1);
        size_t ob = (((size_t)(b*NHEAD+h))*SEQ + t)*64;
        #pragma unroll
        for (int nt=0;nt<4;nt++){
          float rot = (nt < 2) ? -qv[nt+2] : qv[nt-2];
          float cs = (nt & 1) ? c1 : c0, sn = (nt & 1) ? s1 : s0;
          float val = qv[nt]*cs + rot*sn;
          val = (val > 0.f) ? val + 1.f : __expf(val);
          of[ob + nt*16 + m16] = f2b(val);
        }
      }
    }
  } else if (colbase < 2368){
    // resonance params block (bx == 36): stash 64x48 accs in LDS, all threads do coef
    float* pf = (float*)As;               // [64][49] fp32 = 12544 B <= 16384 B
    #pragma unroll
    for (int r=0;r<4;r++){
      int rowl = w*16 + quad*4 + r;
      #pragma unroll
      for (int nt=0;nt<4;nt++){
        int p = nt*16 + m16;
        if (p < 48) pf[rowl*49 + p] = acc[nt][r];
      }
    }
    __syncthreads();
    float tv = temp[0];
    #pragma unroll
    for (int i=0;i<3;i++){
      int idx2 = tid + i*256;             // 0..767 = 64 rows x 12 heads
      int rowl = idx2 / 12, h = idx2 - rowl*12;
      int row = bm + rowl, b = row >> 10, t = row & 1023;
      const float* pr = pf + rowl*49 + h*4;
      float sa = sigf(pr[0]);
      float sp = sigf(pr[1])*3.14159265358979323846f;
      float ca = sigf(pr[2]);
      float cp = sigf(pr[3])*3.14159265358979323846f;
      float z = sa*ca*cosf(sp - cp)*tv;
      float gate = fminf(fmaxf(sigf(z)*1.2f - 0.1f, 0.05f), 0.95f);
      float dd = decay_of(hdec[h]);
      float df = expf((float)(t+1)*logf(dd));
      float g = df/(df + 1e-8f);
      int ci = (b*NHEAD + h)*SEQ + t;
      cKV[ci] = g*gate*(1.f - dd);
      cG[ci]  = 1.f/gate;
    }
  } else {
    // out-gate: silu -> bf16
    int gc0 = colbase - 2368;
    #pragma unroll
    for (int r=0;r<4;r++){
      int row = bm + w*16 + quad*4 + r;
      #pragma unroll
      for (int nt=0;nt<4;nt++){
        int gc = gc0 + nt*16 + m16;
        float v = acc[nt][r];
        v = v/(1.f + __expf(-v));
        gateb[(size_t)row*D_MODEL + gc] = f2b(v);
      }
    }
  }
}

// ---------------- intra-chunk: MFMA scores + num/den + P^T/zP ----------------
__global__ __launch_bounds__(256) void k_intra(const unsigned short* __restrict__ qf,
    const unsigned short* __restrict__ kf, const unsigned short* __restrict__ vf,
    const float* __restrict__ cKVb, const float* __restrict__ cGb,
    const float* __restrict__ hdec, float* __restrict__ numb,
    float* __restrict__ denb, float* __restrict__ Pb, float* __restrict__ zPb)
{
  __shared__ __align__(16) unsigned short Qb[64*PQ];   // Q_f  [t][k]
  __shared__ __align__(16) unsigned short Kb[64*PQ];   // K_f  [s][d]
  __shared__ __align__(16) unsigned short KtS[64*PQ];  // (K_f*cps)^T [d][s]
  __shared__ __align__(16) unsigned short Wb[64*PQ];   // Wn   [t][s]
  __shared__ __align__(16) unsigned short Vt[80*PQ];   // V^T  [e][s]; row64 = invgate; 65..79 = 0
  __shared__ float cn[64], cps[64];
  int bid = blockIdx.x;
  int chunk = bid & 15, bh = bid >> 4, h = bh % NHEAD;
  int tid = threadIdx.x, w = tid >> 6, lane = tid & 63;
  int m16 = lane & 15, quad = lane >> 4;
  size_t base = ((size_t)bh*SEQ + chunk*64)*64;
  float d = decay_of(hdec[h]);
  float l2d = log2f(d);

  if (tid < 64){
    float c = cKVb[bh*SEQ + chunk*64 + tid];
    float pw = exp2f((float)(63 - tid)*l2d);
    cn[tid] = c;
    cps[tid] = c*pw;
    Vt[64*PQ + tid] = f2b(cGb[bh*SEQ + chunk*64 + tid]);
  }
  for (int i = tid; i < 15*PQ; i += 256) Vt[65*PQ + i] = 0;
  __syncthreads();   // cps ready for KtS staging

  #pragma unroll
  for (int i=0;i<2;i++){
    int g = tid + i*256;
    int r = g >> 3, c8 = (g & 7)*8;
    *(short8*)(Qb + r*PQ + c8) = *(const short8*)(qf + base + r*64 + c8);
    *(short8*)(Kb + r*PQ + c8) = *(const short8*)(kf + base + r*64 + c8);
  }
  {
    int s = tid & 63;
    float cpss = cps[s];
    #pragma unroll
    for (int i=0;i<2;i++){
      int c8 = ((tid >> 6) + i*4)*8;
      short8 vv = *(const short8*)(vf + base + s*64 + c8);
      short8 kk = *(const short8*)(kf + base + s*64 + c8);
      #pragma unroll
      for (int j=0;j<8;j++){
        Vt[(c8+j)*PQ + s] = ((unsigned short*)&vv)[j];
        KtS[(c8+j)*PQ + s] = f2b(bf2f(((unsigned short*)&kk)[j])*cpss);
      }
    }
  }
  __syncthreads();

  int trow = w*16 + quad*4;
  for (int stile=0; stile<4; stile++){
    if (stile > w){
      #pragma unroll
      for (int r=0;r<4;r++) Wb[(trow+r)*PQ + stile*16 + m16] = 0;
      continue;
    }
    f32x4 acc = (f32x4){0.f,0.f,0.f,0.f};
    #pragma unroll
    for (int ks=0;ks<2;ks++){
      short8 a = *(const short8*)(Qb + (w*16 + m16)*PQ + ks*32 + quad*8);
      short8 b = *(const short8*)(Kb + (stile*16 + m16)*PQ + ks*32 + quad*8);
      acc = __builtin_amdgcn_mfma_f32_16x16x32_bf16(a, b, acc, 0, 0, 0);
    }
    int s = stile*16 + m16;
    float cns = cn[s];
    #pragma unroll
    for (int r=0;r<4;r++){
      int t = trow + r;
      float wv = 0.f;
      if (s <= t) wv = acc[r]*exp2f((float)(t-s)*l2d)*cns;
      Wb[t*PQ + s] = f2b(wv);
    }
  }
  __syncthreads();

  {
    f32x4 acc[5];
    #pragma unroll
    for (int et=0;et<5;et++) acc[et] = (f32x4){0.f,0.f,0.f,0.f};
    #pragma unroll
    for (int et=0;et<5;et++)
      #pragma unroll
      for (int ks=0;ks<2;ks++){
        short8 a = *(const short8*)(Wb + (w*16 + m16)*PQ + ks*32 + quad*8);
        short8 b = *(const short8*)(Vt + (et*16 + m16)*PQ + ks*32 + quad*8);
        acc[et] = __builtin_amdgcn_mfma_f32_16x16x32_bf16(a, b, acc[et], 0, 0, 0);
      }
    #pragma unroll
    for (int et=0;et<4;et++)
      #pragma unroll
      for (int r=0;r<4;r++)
        numb[base + (size_t)(trow+r)*64 + et*16 + m16] = acc[et][r];
    if (m16 == 0){
      #pragma unroll
      for (int r=0;r<4;r++)
        denb[bh*SEQ + chunk*64 + trow + r] = acc[4][r];
    }
  }
  {
    #pragma unroll
    for (int j=0;j<5;j++){
      int tIdx = w + 4*j;
      int et = tIdx >> 2, dt = tIdx & 3;
      f32x4 acc = (f32x4){0.f,0.f,0.f,0.f};
      #pragma unroll
      for (int ks=0;ks<2;ks++){
        short8 a = *(const short8*)(Vt  + (et*16 + m16)*PQ + ks*32 + quad*8);
        short8 b = *(const short8*)(KtS + (dt*16 + m16)*PQ + ks*32 + quad*8);
        acc = __builtin_amdgcn_mfma_f32_16x16x32_bf16(a, b, acc, 0, 0, 0);
      }
      if (et < 4){
        #pragma unroll
        for (int r=0;r<4;r++)
          Pb[(size_t)bid*4096 + (et*16 + quad*4 + r)*64 + dt*16 + m16] = acc[r];
      } else {
        if (quad == 0) zPb[bid*64 + dt*16 + m16] = acc[0];
      }
    }
  }
}

// ---------------- cross-chunk: prefix-combine + attention out (bf16) + row sumsq ----
__global__ __launch_bounds__(256) void k_cross(const unsigned short* __restrict__ qf,
    const float* __restrict__ Pb, const float* __restrict__ zPb,
    const float* __restrict__ numb, const float* __restrict__ denb,
    const float* __restrict__ hdec, unsigned short* __restrict__ attnb,
    float* __restrict__ sumsq)
{
  __shared__ __align__(16) unsigned short Qb[64*PQ];   // Q_f [t][k]
  __shared__ __align__(16) unsigned short Sp[80*PQ];   // S [e][d]; row64 = zprev; 65..79 = 0
  __shared__ float den_sm[64];
  int bid = blockIdx.x;
  int swz = (bid & 7)*48 + (bid >> 3);     // 384 = 8*48, bijective
  int chunk = swz & 15, bh = swz >> 4;
  int h = bh % NHEAD, b = bh / NHEAD;
  int tid = threadIdx.x, w = tid >> 6, lane = tid & 63;
  int m16 = lane & 15, quad = lane >> 4;
  size_t base = ((size_t)bh*SEQ + chunk*64)*64;
  float d = decay_of(hdec[h]);
  float l2d = log2f(d);
  float d64l2 = 64.f*l2d;

  // stage Q
  #pragma unroll
  for (int i=0;i<2;i++){
    int g = tid + i*256;
    int r = g >> 3, c8 = (g & 7)*8;
    *(short8*)(Qb + r*PQ + c8) = *(const short8*)(qf + base + r*64 + c8);
  }

  // prefix-combine P -> S_prev (each thread owns 16 of the 4096 elements)
  {
    int r = tid >> 3, c8 = (tid & 7)*8;    // rows r and r+32, cols c8..c8+7
    float a0[8], a1[8];
    #pragma unroll
    for (int j=0;j<8;j++){ a0[j]=0.f; a1[j]=0.f; }
    for (int c=0;c<chunk;c++){
      float wgt = exp2f((float)(chunk-1-c)*d64l2);
      const float* ps = Pb + ((size_t)(bh*NCHUNK + c))*4096;
      float4 p0 = *(const float4*)(ps + r*64 + c8);
      float4 p1 = *(const float4*)(ps + r*64 + c8 + 4);
      float4 p2 = *(const float4*)(ps + (r+32)*64 + c8);
      float4 p3 = *(const float4*)(ps + (r+32)*64 + c8 + 4);
      a0[0]+=wgt*p0.x; a0[1]+=wgt*p0.y; a0[2]+=wgt*p0.z; a0[3]+=wgt*p0.w;
      a0[4]+=wgt*p1.x; a0[5]+=wgt*p1.y; a0[6]+=wgt*p1.z; a0[7]+=wgt*p1.w;
      a1[0]+=wgt*p2.x; a1[1]+=wgt*p2.y; a1[2]+=wgt*p2.z; a1[3]+=wgt*p2.w;
      a1[4]+=wgt*p3.x; a1[5]+=wgt*p3.y; a1[6]+=wgt*p3.z; a1[7]+=wgt*p3.w;
    }
    #pragma unroll
    for (int j=0;j<8;j++){
      Sp[r*PQ + c8 + j]      = f2b(a0[j]);
      Sp[(r+32)*PQ + c8 + j] = f2b(a1[j]);
    }
  }
  // z_prev (row 64) and zero pad rows 65..79
  if (tid < 64){
    float z = 0.f;
    for (int c=0;c<chunk;c++)
      z += exp2f((float)(chunk-1-c)*d64l2) * zPb[(bh*NCHUNK + c)*64 + tid];
    Sp[64*PQ + tid] = f2b(z);
  }
  for (int i = tid; i < 15*PQ; i += 256) Sp[65*PQ + i] = 0;
  __syncthreads();

  f32x4 acc[5];
  #pragma unroll
  for (int et=0;et<5;et++) acc[et] = (f32x4){0.f,0.f,0.f,0.f};
  #pragma unroll
  for (int et=0;et<5;et++)
    #pragma unroll
    for (int ks=0;ks<2;ks++){
      short8 a = *(const short8*)(Qb + (w*16 + m16)*PQ + ks*32 + quad*8);
      short8 bb = *(const short8*)(Sp + (et*16 + m16)*PQ + ks*32 + quad*8);
      acc[et] = __builtin_amdgcn_mfma_f32_16x16x32_bf16(a, bb, acc[et], 0, 0, 0);
    }
  int trow = w*16 + quad*4;
  if (m16 == 0){
    #pragma unroll
    for (int r=0;r<4;r++){
      int tl = trow + r;
      float pw = exp2f((float)(tl+1)*l2d);
      float den = fmaxf(denb[bh*SEQ + chunk*64 + tl] + pw*acc[4][r], 1e-5f);
      den_sm[tl] = 1.f/den;
    }
  }
  __syncthreads();
  #pragma unroll
  for (int r=0;r<4;r++){
    int tl = trow + r;
    float pw = exp2f((float)(tl+1)*l2d);
    float invden = den_sm[tl];
    int rowg = b*SEQ + chunk*64 + tl;
    float ls = 0.f;
    #pragma unroll
    for (int et=0;et<4;et++){
      int e = et*16 + m16;
      float ov = (numb[base + (size_t)tl*64 + e] + pw*acc[et][r])*invden;
      attnb[(size_t)rowg*D_MODEL + h*64 + e] = f2b(ov);
      ls += ov*ov;
    }
    ls += __shfl_xor(ls, 1, 64); ls += __shfl_xor(ls, 2, 64);
    ls += __shfl_xor(ls, 4, 64); ls += __shfl_xor(ls, 8, 64);
    if (m16 == 0) atomicAdd(&sumsq[rowg], ls);
  }
}

extern "C" void kernel_launch(void* const* d_in, const int* in_sizes, int n_in,
                              void* d_out, int out_size, void* d_ws, size_t ws_size,
                              hipStream_t stream)
{
  (void)in_sizes; (void)n_in; (void)out_size; (void)ws_size;
  const float* x       = (const float*)d_in[0];
  const float* w_ln    = (const float*)d_in[1];
  const float* w_comp  = (const float*)d_in[2];
  const float* w_qkv   = (const float*)d_in[3];
  const float* w_reso  = (const float*)d_in[4];
  const float* w_qn    = (const float*)d_in[5];
  const float* w_kn    = (const float*)d_in[6];
  const float* hdec    = (const float*)d_in[7];
  const float* temp    = (const float*)d_in[8];
  const float* w_ogate = (const float*)d_in[9];
  const float* w_proj  = (const float*)d_in[10];
  const float* w_mn    = (const float*)d_in[11];
  float* ws = (float*)d_ws;
  float* out = (float*)d_out;

  // fp32 region (floats)
  const size_t o_cKV    = 0;
  const size_t o_cG     = o_cKV    + (size_t)NBH*SEQ;
  const size_t o_den    = o_cG     + (size_t)NBH*SEQ;
  const size_t o_P      = o_den    + (size_t)NBH*SEQ;          // 24*16*4096 ([e][d])
  const size_t o_zP     = o_P      + (size_t)NBH*NCHUNK*4096;
  const size_t o_sumsq  = o_zP     + (size_t)NBH*NCHUNK*64;    // 2048 floats
  const size_t o_numb   = o_sumsq  + (size_t)NROWS;
  const size_t o_end    = o_numb   + (size_t)NBH*SEQ*64;

  // bf16 region (ushorts)
  unsigned short* bws = (unsigned short*)(ws + o_end);
  const size_t u_xn     = 0;
  const size_t u_latent = u_xn     + (size_t)NROWS*D_MODEL;
  const size_t u_memn   = u_latent + (size_t)NROWS*LATD;       // bf16 attn (A of out-GEMM)
  const size_t u_q      = u_memn   + (size_t)NROWS*D_MODEL;
  const size_t u_k      = u_q      + (size_t)NBH*SEQ*64;
  const size_t u_v      = u_k      + (size_t)NBH*SEQ*64;
  const size_t u_gate   = u_v      + (size_t)NBH*SEQ*64;       // 2048*768
  const size_t u_wtc    = u_gate   + (size_t)NROWS*D_MODEL;
  const size_t u_wtq    = u_wtc    + (size_t)LATD*D_MODEL;     // 2368*512 (qkv+params)
  const size_t u_wtg    = u_wtq    + (size_t)2368*LATD;        // contiguous: fused BT rows 2368..3135
  const size_t u_wtp    = u_wtg    + (size_t)D_MODEL*LATD;     // w_proj^T with w_mn folded

  // 1. weight converts (w_mn folded into wtp) + rmsnorm(x) + sumsq zero
  k_prep<<<2688, 256, 0, stream>>>(x, w_ln, bws + u_xn,
      w_comp, w_qkv, w_reso, w_ogate, w_proj, w_mn,
      bws + u_wtc, bws + u_wtq, bws + u_wtg, bws + u_wtp, ws + o_sumsq);
  // 2. latent = silu(xn @ w_compress) -> bf16   (64x64 tiles, 256 blocks, pipelined)
  k_gemm64<<<256, 256, 0, stream>>>(bws + u_xn, bws + u_wtc,
      nullptr, bws + u_latent, nullptr, nullptr, NROWS, LATD, D_MODEL, 1, LATD/64);
  // 3. fused qkv+params+gate GEMM, 64x64 tiles (1568 blocks, pipelined)
  k_gemm_fused64<<<1568, 256, 0, stream>>>(bws + u_latent, bws + u_wtq,
      w_qn, w_kn, hdec, temp, bws + u_q, bws + u_k, bws + u_v,
      ws + o_cKV, ws + o_cG, bws + u_gate);
  // 4. intra-chunk (MFMA)
  k_intra<<<NBH*NCHUNK, 256, 0, stream>>>(bws + u_q, bws + u_k, bws + u_v,
      ws + o_cKV, ws + o_cG, hdec, ws + o_numb, ws + o_den, ws + o_P, ws + o_zP);
  // 5. cross-chunk combine + bf16 attn + row sumsq (384 blocks, swizzled)
  k_cross<<<NBH*NCHUNK, 256, 0, stream>>>(bws + u_q, ws + o_P, ws + o_zP,
      ws + o_numb, ws + o_den, hdec, bws + u_memn, ws + o_sumsq);
  // 6. out = rmsnorm-scale * (attn_bf16 @ wtp') * gate  (384 blocks, pipelined)
  k_gemm64<<<384, 256, 0, stream>>>(bws + u_memn, bws + u_wtp,
      out, nullptr, bws + u_gate, ws + o_sumsq, NROWS, D_MODEL, D_MODEL, 3, D_MODEL/64);
}

// Round 9
// 149.489 us; speedup vs baseline: 1.5124x; 1.0484x over previous
//
#include <hip/hip_runtime.h>
#include <hip/hip_bf16.h>
#include <math.h>

// Problem constants (B=2, L=1024, D=768, H=12, DH=64, LAT=512)
#define D_MODEL 768
#define NHEAD   12
#define LATD    512
#define BATCH   2
#define SEQ     1024
#define NROWS   (BATCH*SEQ)          // 2048
#define NCHUNK  (SEQ/64)             // 16
#define NBH     (BATCH*NHEAD)        // 24
#define NFUSE   3200                 // qkv 2304 + params pad 128 + gate 768
#define PQ      72                   // LDS ushort pitch (144 B rows, 16B-aligned frags)

using short8 = __attribute__((ext_vector_type(8))) short;
using f32x4  = __attribute__((ext_vector_type(4))) float;

__device__ __forceinline__ float sigf(float x){ return 1.f/(1.f+expf(-x)); }
__device__ __forceinline__ float decay_of(float hd){
  float d = 0.3f + 0.65f*sigf(hd);
  return fminf(fmaxf(d, 1e-5f), 0.999f);
}
__device__ __forceinline__ unsigned short f2b(float f){
  __hip_bfloat16 h = __float2bfloat16(f);
  return *reinterpret_cast<unsigned short*>(&h);
}
__device__ __forceinline__ float bf2f(unsigned short u){
  unsigned int x = ((unsigned int)u) << 16;
  return __uint_as_float(x);
}
__device__ __forceinline__ void async16(const unsigned short* g, unsigned short* l){
  __builtin_amdgcn_global_load_lds((const __attribute__((address_space(1))) void*)g,
                                   (__attribute__((address_space(3))) void*)l, 16, 0, 0);
}

// shared rmsnorm-row body (D=768), one block of 256 per row
__device__ __forceinline__ void rms_row(const float* __restrict__ xr,
    const float* __restrict__ w, unsigned short* __restrict__ yr,
    int tid, float* red)
{
  float v0 = xr[tid], v1 = xr[tid+256], v2 = xr[tid+512];
  float s = v0*v0 + v1*v1 + v2*v2;
  #pragma unroll
  for (int off=32; off; off>>=1) s += __shfl_xor(s, off, 64);
  if ((tid & 63) == 0) red[tid>>6] = s;
  __syncthreads();
  s = red[0]+red[1]+red[2]+red[3];
  float sc = rsqrtf(s*(1.f/(float)D_MODEL) + 1e-6f);
  yr[tid]     = f2b(v0*sc*w[tid]);
  yr[tid+256] = f2b(v1*sc*w[tid+256]);
  yr[tid+512] = f2b(v2*sc*w[tid+512]);
}

// ---------------- prep: weight converts + rmsnorm(x) + sumsq zero, ONE launch ------
__global__ __launch_bounds__(256) void k_prep(
    const float* __restrict__ x, const float* __restrict__ w_ln,
    unsigned short* __restrict__ xn,
    const float* __restrict__ wc, const float* __restrict__ wq,
    const float* __restrict__ wr, const float* __restrict__ wg,
    const float* __restrict__ wp, const float* __restrict__ w_mn,
    unsigned short* __restrict__ wtc, unsigned short* __restrict__ wtq,
    unsigned short* __restrict__ wtg, unsigned short* __restrict__ wtp,
    float* __restrict__ sumsq)
{
  __shared__ unsigned short tile[64][65];
  __shared__ float red[4];
  int blk = blockIdx.x, t = threadIdx.x;
  if (blk >= 640){
    int row = blk - 640;
    rms_row(x + (size_t)row*D_MODEL, w_ln, xn + (size_t)row*D_MODEL, t, red);
    return;
  }
  const float* W; unsigned short* WT; int K, N, bx, by;
  const float* kscale = nullptr;
  if (blk < 96){ W=wc; WT=wtc; K=768; N=512; bx=blk&7; by=blk>>3; }
  else if (blk < 384){ int i=blk-96;  W=wq; WT=wtq; K=512; N=2304; bx=i%36; by=i/36; }
  else if (blk < 480){ int i=blk-384; W=wg; WT=wtg; K=512; N=768;  bx=i%12; by=i/12; }
  else if (blk < 624){ int i=blk-480; W=wp; WT=wtp; K=768; N=768;  bx=i%12; by=i/12; kscale=w_mn; }
  else {
    // w_reso [512][48] -> wtq rows 2304..2431 (zero-pad 2352..2431); blk 624 zeroes sumsq
    int i = blk - 624;                    // 0..15
    if (i == 0){
      #pragma unroll
      for (int j=0;j<8;j++) sumsq[t + j*256] = 0.f;
    }
    #pragma unroll
    for (int j=0;j<16;j++){
      int e = i*4096 + t + j*256;         // 0..65535
      int n = 2304 + (e >> 9), k = e & 511;
      float v = (n < 2352) ? wr[(size_t)k*48 + (n-2304)] : 0.f;
      wtq[(size_t)n*512 + k] = f2b(v);
    }
    return;
  }
  int k0 = by*64, n0 = bx*64, cr = t >> 6, cc = t & 63;
  #pragma unroll
  for (int i=0;i<16;i++){
    int r = cr + i*4;
    float v = W[(size_t)(k0+r)*N + n0 + cc];
    if (kscale) v *= kscale[k0+r];
    tile[r][cc] = f2b(v);
  }
  __syncthreads();
  #pragma unroll
  for (int i=0;i<16;i++){
    int nn = cr + i*4;
    WT[(size_t)(n0+nn)*K + k0 + cc] = tile[cc][nn];
  }
}

// ---------------- 64x64-tile bf16 MFMA GEMM, double-buffered 2-phase pipeline ------
// act: 1 = silu (bf16 Cb); 3 = rmsnorm-scale (sums) * aux gate (fp32 Cf)
__global__ __launch_bounds__(256) void k_gemm64(const unsigned short* __restrict__ A,
    const unsigned short* __restrict__ BT, float* __restrict__ Cf,
    unsigned short* __restrict__ Cb, const unsigned short* __restrict__ auxb,
    const float* __restrict__ sums, int M, int N, int K, int act, int NX)
{
  __shared__ unsigned short As[2*64*64];   // double-buffered
  __shared__ unsigned short Bs[2*64*64];
  int tid = threadIdx.x;
  int w = tid >> 6, lane = tid & 63;
  int m16 = lane & 15, quad = lane >> 4;
  int bid = blockIdx.x, cpx = gridDim.x >> 3;
  int swz = (bid & 7)*cpx + (bid >> 3);
  int bx = swz % NX, by = swz / NX;
  int bm = by*64, bn = bx*64;

  f32x4 acc[4];
  #pragma unroll
  for (int nt=0;nt<4;nt++) acc[nt] = (f32x4){0.f,0.f,0.f,0.f};

  int nk = K >> 6;
  // prologue: stage tile 0 into buf 0
  #pragma unroll
  for (int i=0;i<2;i++){
    int g = (w*2 + i)*64 + lane;
    int m = g >> 3, c = (g & 7) ^ (m & 7);
    async16(A  + (size_t)(bm+m)*K + c*8, As + (w*2+i)*512);
    async16(BT + (size_t)(bn+m)*K + c*8, Bs + (w*2+i)*512);
  }
  __syncthreads();
  int cur = 0;
  for (int t = 0; t < nk; ++t){
    if (t+1 < nk){
      int kk = (t+1) << 6;
      int nb = cur ^ 1;
      #pragma unroll
      for (int i=0;i<2;i++){
        int g = (w*2 + i)*64 + lane;
        int m = g >> 3, c = (g & 7) ^ (m & 7);
        async16(A  + (size_t)(bm+m)*K + kk + c*8, As + nb*4096 + (w*2+i)*512);
        async16(BT + (size_t)(bn+m)*K + kk + c*8, Bs + nb*4096 + (w*2+i)*512);
      }
    }
    #pragma unroll
    for (int s=0;s<2;s++){
      int row = w*16 + m16;
      short8 af = *(const short8*)(As + cur*4096 + (row*8 + ((s*4 + quad) ^ (row & 7)))*8);
      #pragma unroll
      for (int nt=0;nt<4;nt++){
        int n = nt*16 + m16;
        short8 bf = *(const short8*)(Bs + cur*4096 + (n*8 + ((s*4 + quad) ^ (n & 7)))*8);
        acc[nt] = __builtin_amdgcn_mfma_f32_16x16x32_bf16(af, bf, acc[nt], 0, 0, 0);
      }
    }
    __syncthreads();
    cur ^= 1;
  }
  #pragma unroll
  for (int r=0;r<4;r++){
    int row = bm + w*16 + quad*4 + r;
    float rowsc = 1.f;
    if (act == 3) rowsc = rsqrtf(sums[row]*(1.f/(float)D_MODEL) + 1e-6f);
    #pragma unroll
    for (int nt=0;nt<4;nt++){
      int col = bn + nt*16 + m16;
      float v = acc[nt][r];
      if (act == 1) v = v/(1.f + __expf(-v));
      else if (act == 3) v = v*rowsc*bf2f(auxb[(size_t)row*N + col]);
      if (Cf) Cf[(size_t)row*N + col] = v;
      if (Cb) Cb[(size_t)row*N + col] = f2b(v);
    }
  }
}

// ---------------- fused GEMM: [qkv | params | gate] = latent @ BT (N=3200) ----------
// Double-buffered 2-phase pipeline; epilogue does feat (rmsnorm+rope+elu+1) + coef.
__global__ __launch_bounds__(256) void k_gemm_fused(const unsigned short* __restrict__ A,
    const unsigned short* __restrict__ BT, const float* __restrict__ w_qn,
    const float* __restrict__ w_kn, const float* __restrict__ hdec,
    const float* __restrict__ temp, unsigned short* __restrict__ qf,
    unsigned short* __restrict__ kf, unsigned short* __restrict__ vf,
    float* __restrict__ cKV, float* __restrict__ cG,
    unsigned short* __restrict__ gateb)
{
  __shared__ __align__(16) unsigned short SM[4*128*64];   // As[2] | Bs[2]; pf re-alias later
  unsigned short* As = SM;                 // [2][128*64]
  unsigned short* Bs = SM + 2*128*64;      // [2][128*64]
  const int K = LATD;
  int tid = threadIdx.x;
  int w = tid >> 6, lane = tid & 63;
  int wm = (w >> 1)*64, wn = (w & 1)*64;
  int m16 = lane & 15, quad = lane >> 4;
  int bid = blockIdx.x;
  int swz = (bid & 7)*50 + (bid >> 3);   // 400 = 8*50, bijective
  int bx = swz >> 4, by = swz & 15;      // by fastest within an XCD chunk
  int bm = by*128, bn = bx*128;

  f32x4 acc[4][4];
  #pragma unroll
  for (int i=0;i<4;i++)
    #pragma unroll
    for (int j=0;j<4;j++) acc[i][j] = (f32x4){0.f,0.f,0.f,0.f};

  const int nk = K >> 6;                 // 8
  // prologue: stage tile 0 into buf 0
  #pragma unroll
  for (int i=0;i<4;i++){
    int g = (w*4 + i)*64 + lane;
    int m = g >> 3, c = (g & 7) ^ (m & 7);
    async16(A  + (size_t)(bm+m)*K + c*8, As + (w*4+i)*512);
    async16(BT + (size_t)(bn+m)*K + c*8, Bs + (w*4+i)*512);
  }
  __syncthreads();
  int cur = 0;
  for (int t = 0; t < nk; ++t){
    if (t+1 < nk){
      int kk = (t+1) << 6;
      int nb = cur ^ 1;
      #pragma unroll
      for (int i=0;i<4;i++){
        int g = (w*4 + i)*64 + lane;
        int m = g >> 3, c = (g & 7) ^ (m & 7);
        async16(A  + (size_t)(bm+m)*K + kk + c*8, As + nb*8192 + (w*4+i)*512);
        async16(BT + (size_t)(bn+m)*K + kk + c*8, Bs + nb*8192 + (w*4+i)*512);
      }
    }
    #pragma unroll
    for (int s=0;s<2;s++){
      short8 af[4], bf[4];
      #pragma unroll
      for (int mt=0;mt<4;mt++){
        int m = wm + mt*16 + m16;
        int idx = m*8 + ((s*4 + quad) ^ (m & 7));
        af[mt] = *(const short8*)(As + cur*8192 + idx*8);
      }
      #pragma unroll
      for (int nt=0;nt<4;nt++){
        int n = wn + nt*16 + m16;
        int idx = n*8 + ((s*4 + quad) ^ (n & 7));
        bf[nt] = *(const short8*)(Bs + cur*8192 + idx*8);
      }
      #pragma unroll
      for (int mt=0;mt<4;mt++)
        #pragma unroll
        for (int nt=0;nt<4;nt++)
          acc[mt][nt] = __builtin_amdgcn_mfma_f32_16x16x32_bf16(af[mt], bf[nt], acc[mt][nt], 0, 0, 0);
    }
    __syncthreads();
    cur ^= 1;
  }

  int colbase = bn + wn;                // 64-aligned; wave owns cols [colbase, colbase+64)
  if (colbase < 2304){
    int sec = colbase >= 1536 ? 2 : (colbase >= 768 ? 1 : 0);   // 0=q 1=k 2=v
    int h = (colbase - sec*768) >> 6;
    if (sec == 2){
      #pragma unroll
      for (int mt=0;mt<4;mt++)
        #pragma unroll
        for (int r=0;r<4;r++){
          int row = bm + wm + mt*16 + quad*4 + r;
          int b = row >> 10, t = row & 1023;
          size_t ob = (((size_t)(b*NHEAD+h))*SEQ + t)*64;
          #pragma unroll
          for (int nt=0;nt<4;nt++)
            vf[ob + nt*16 + m16] = f2b(acc[mt][nt][r]);
        }
    } else {
      const float* wnp = sec ? w_kn : w_qn;
      unsigned short* of = sec ? kf : qf;
      float wv4[4];
      #pragma unroll
      for (int nt=0;nt<4;nt++) wv4[nt] = wnp[nt*16 + m16];
      float inv0 = exp2f(-(float)m16*(1.f/32.f)*13.28771237954945f);  // 10000^{-m16/32}
      float inv1 = inv0 * 0.01f;                                      // * 10000^{-16/32}
      #pragma unroll
      for (int mt=0;mt<4;mt++)
        #pragma unroll
        for (int r=0;r<4;r++){
          int row = bm + wm + mt*16 + quad*4 + r;
          int b = row >> 10, t = row & 1023;
          float s = 0.f;
          #pragma unroll
          for (int nt=0;nt<4;nt++) s += acc[mt][nt][r]*acc[mt][nt][r];
          s += __shfl_xor(s, 1, 64); s += __shfl_xor(s, 2, 64);
          s += __shfl_xor(s, 4, 64); s += __shfl_xor(s, 8, 64);
          float rs = rsqrtf(s*(1.f/64.f) + 1e-6f);
          float qv[4];
          #pragma unroll
          for (int nt=0;nt<4;nt++) qv[nt] = acc[mt][nt][r]*rs*wv4[nt];
          float s0,c0,s1,c1;
          __sincosf((float)t*inv0, &s0, &c0);
          __sincosf((float)t*inv1, &s1, &c1);
          size_t ob = (((size_t)(b*NHEAD+h))*SEQ + t)*64;
          #pragma unroll
          for (int nt=0;nt<4;nt++){
            float rot = (nt < 2) ? -qv[nt+2] : qv[nt-2];
            float cs = (nt & 1) ? c1 : c0, sn = (nt & 1) ? s1 : s0;
            float val = qv[nt]*cs + rot*sn;
            val = (val > 0.f) ? val + 1.f : __expf(val);
            of[ob + nt*16 + m16] = f2b(val);
          }
        }
    }
  } else if (colbase < 2432){
    // resonance params block: all 4 waves of this block land here -> block sync OK.
    float* pf = (float*)SM;               // [128][49] fp32 = 25088 B
    if (colbase == 2304){
      #pragma unroll
      for (int mt=0;mt<4;mt++)
        #pragma unroll
        for (int r=0;r<4;r++){
          int rowl = wm + mt*16 + quad*4 + r;
          #pragma unroll
          for (int nt=0;nt<4;nt++){
            int p = nt*16 + m16;
            if (p < 48) pf[rowl*49 + p] = acc[mt][nt][r];
          }
        }
    }
    __syncthreads();
    float tv = temp[0];
    #pragma unroll
    for (int i=0;i<6;i++){
      int idx2 = tid + i*256;             // 0..1535 = 128 rows x 12 heads
      int rowl = idx2 / 12, h = idx2 - rowl*12;
      int row = bm + rowl, b = row >> 10, t = row & 1023;
      const float* pr = pf + rowl*49 + h*4;
      float sa = sigf(pr[0]);
      float sp = sigf(pr[1])*3.14159265358979323846f;
      float ca = sigf(pr[2]);
      float cp = sigf(pr[3])*3.14159265358979323846f;
      float z = sa*ca*cosf(sp - cp)*tv;
      float gate = fminf(fmaxf(sigf(z)*1.2f - 0.1f, 0.05f), 0.95f);
      float dd = decay_of(hdec[h]);
      float df = expf((float)(t+1)*logf(dd));
      float g = df/(df + 1e-8f);
      int ci = (b*NHEAD + h)*SEQ + t;
      cKV[ci] = g*gate*(1.f - dd);
      cG[ci]  = 1.f/gate;
    }
  } else {
    // out-gate: silu -> bf16
    #pragma unroll
    for (int mt=0;mt<4;mt++)
      #pragma unroll
      for (int r=0;r<4;r++){
        int row = bm + wm + mt*16 + quad*4 + r;
        #pragma unroll
        for (int nt=0;nt<4;nt++){
          int gc = colbase + nt*16 + m16 - 2432;
          float v = acc[mt][nt][r];
          v = v/(1.f + __expf(-v));
          gateb[(size_t)row*D_MODEL + gc] = f2b(v);
        }
      }
  }
}

// ---------------- intra-chunk: MFMA scores + num/den + P^T/zP ----------------
__global__ __launch_bounds__(256) void k_intra(const unsigned short* __restrict__ qf,
    const unsigned short* __restrict__ kf, const unsigned short* __restrict__ vf,
    const float* __restrict__ cKVb, const float* __restrict__ cGb,
    const float* __restrict__ hdec, float* __restrict__ numb,
    float* __restrict__ denb, float* __restrict__ Pb, float* __restrict__ zPb)
{
  __shared__ __align__(16) unsigned short Qb[64*PQ];   // Q_f  [t][k]
  __shared__ __align__(16) unsigned short Kb[64*PQ];   // K_f  [s][d]
  __shared__ __align__(16) unsigned short KtS[64*PQ];  // (K_f*cps)^T [d][s]
  __shared__ __align__(16) unsigned short Wb[64*PQ];   // Wn   [t][s]
  __shared__ __align__(16) unsigned short Vt[80*PQ];   // V^T  [e][s]; row64 = invgate; 65..79 = 0
  __shared__ float cn[64], cps[64];
  int bid = blockIdx.x;
  int chunk = bid & 15, bh = bid >> 4, h = bh % NHEAD;
  int tid = threadIdx.x, w = tid >> 6, lane = tid & 63;
  int m16 = lane & 15, quad = lane >> 4;
  size_t base = ((size_t)bh*SEQ + chunk*64)*64;
  float d = decay_of(hdec[h]);
  float l2d = log2f(d);

  if (tid < 64){
    float c = cKVb[bh*SEQ + chunk*64 + tid];
    float pw = exp2f((float)(63 - tid)*l2d);
    cn[tid] = c;
    cps[tid] = c*pw;
    Vt[64*PQ + tid] = f2b(cGb[bh*SEQ + chunk*64 + tid]);
  }
  for (int i = tid; i < 15*PQ; i += 256) Vt[65*PQ + i] = 0;
  __syncthreads();   // cps ready for KtS staging

  #pragma unroll
  for (int i=0;i<2;i++){
    int g = tid + i*256;
    int r = g >> 3, c8 = (g & 7)*8;
    *(short8*)(Qb + r*PQ + c8) = *(const short8*)(qf + base + r*64 + c8);
    *(short8*)(Kb + r*PQ + c8) = *(const short8*)(kf + base + r*64 + c8);
  }
  {
    int s = tid & 63;
    float cpss = cps[s];
    #pragma unroll
    for (int i=0;i<2;i++){
      int c8 = ((tid >> 6) + i*4)*8;
      short8 vv = *(const short8*)(vf + base + s*64 + c8);
      short8 kk = *(const short8*)(kf + base + s*64 + c8);
      #pragma unroll
      for (int j=0;j<8;j++){
        Vt[(c8+j)*PQ + s] = ((unsigned short*)&vv)[j];
        KtS[(c8+j)*PQ + s] = f2b(bf2f(((unsigned short*)&kk)[j])*cpss);
      }
    }
  }
  __syncthreads();

  int trow = w*16 + quad*4;
  for (int stile=0; stile<4; stile++){
    if (stile > w){
      #pragma unroll
      for (int r=0;r<4;r++) Wb[(trow+r)*PQ + stile*16 + m16] = 0;
      continue;
    }
    f32x4 acc = (f32x4){0.f,0.f,0.f,0.f};
    #pragma unroll
    for (int ks=0;ks<2;ks++){
      short8 a = *(const short8*)(Qb + (w*16 + m16)*PQ + ks*32 + quad*8);
      short8 b = *(const short8*)(Kb + (stile*16 + m16)*PQ + ks*32 + quad*8);
      acc = __builtin_amdgcn_mfma_f32_16x16x32_bf16(a, b, acc, 0, 0, 0);
    }
    int s = stile*16 + m16;
    float cns = cn[s];
    #pragma unroll
    for (int r=0;r<4;r++){
      int t = trow + r;
      float wv = 0.f;
      if (s <= t) wv = acc[r]*exp2f((float)(t-s)*l2d)*cns;
      Wb[t*PQ + s] = f2b(wv);
    }
  }
  __syncthreads();

  {
    f32x4 acc[5];
    #pragma unroll
    for (int et=0;et<5;et++) acc[et] = (f32x4){0.f,0.f,0.f,0.f};
    #pragma unroll
    for (int et=0;et<5;et++)
      #pragma unroll
      for (int ks=0;ks<2;ks++){
        short8 a = *(const short8*)(Wb + (w*16 + m16)*PQ + ks*32 + quad*8);
        short8 b = *(const short8*)(Vt + (et*16 + m16)*PQ + ks*32 + quad*8);
        acc[et] = __builtin_amdgcn_mfma_f32_16x16x32_bf16(a, b, acc[et], 0, 0, 0);
      }
    #pragma unroll
    for (int et=0;et<4;et++)
      #pragma unroll
      for (int r=0;r<4;r++)
        numb[base + (size_t)(trow+r)*64 + et*16 + m16] = acc[et][r];
    if (m16 == 0){
      #pragma unroll
      for (int r=0;r<4;r++)
        denb[bh*SEQ + chunk*64 + trow + r] = acc[4][r];
    }
  }
  {
    #pragma unroll
    for (int j=0;j<5;j++){
      int tIdx = w + 4*j;
      int et = tIdx >> 2, dt = tIdx & 3;
      f32x4 acc = (f32x4){0.f,0.f,0.f,0.f};
      #pragma unroll
      for (int ks=0;ks<2;ks++){
        short8 a = *(const short8*)(Vt  + (et*16 + m16)*PQ + ks*32 + quad*8);
        short8 b = *(const short8*)(KtS + (dt*16 + m16)*PQ + ks*32 + quad*8);
        acc = __builtin_amdgcn_mfma_f32_16x16x32_bf16(a, b, acc, 0, 0, 0);
      }
      if (et < 4){
        #pragma unroll
        for (int r=0;r<4;r++)
          Pb[(size_t)bid*4096 + (et*16 + quad*4 + r)*64 + dt*16 + m16] = acc[r];
      } else {
        if (quad == 0) zPb[bid*64 + dt*16 + m16] = acc[0];
      }
    }
  }
}

// ---------------- cross-chunk: prefix-combine + attention out (bf16) + row sumsq ----
__global__ __launch_bounds__(256) void k_cross(const unsigned short* __restrict__ qf,
    const float* __restrict__ Pb, const float* __restrict__ zPb,
    const float* __restrict__ numb, const float* __restrict__ denb,
    const float* __restrict__ hdec, unsigned short* __restrict__ attnb,
    float* __restrict__ sumsq)
{
  __shared__ __align__(16) unsigned short Qb[64*PQ];   // Q_f [t][k]
  __shared__ __align__(16) unsigned short Sp[80*PQ];   // S [e][d]; row64 = zprev; 65..79 = 0
  __shared__ float den_sm[64];
  int bid = blockIdx.x;
  int swz = (bid & 7)*48 + (bid >> 3);     // 384 = 8*48, bijective
  int chunk = swz & 15, bh = swz >> 4;
  int h = bh % NHEAD, b = bh / NHEAD;
  int tid = threadIdx.x, w = tid >> 6, lane = tid & 63;
  int m16 = lane & 15, quad = lane >> 4;
  size_t base = ((size_t)bh*SEQ + chunk*64)*64;
  float d = decay_of(hdec[h]);
  float l2d = log2f(d);
  float d64l2 = 64.f*l2d;

  // stage Q
  #pragma unroll
  for (int i=0;i<2;i++){
    int g = tid + i*256;
    int r = g >> 3, c8 = (g & 7)*8;
    *(short8*)(Qb + r*PQ + c8) = *(const short8*)(qf + base + r*64 + c8);
  }

  // prefix-combine P -> S_prev (each thread owns 16 of the 4096 elements)
  {
    int r = tid >> 3, c8 = (tid & 7)*8;    // rows r and r+32, cols c8..c8+7
    float a0[8], a1[8];
    #pragma unroll
    for (int j=0;j<8;j++){ a0[j]=0.f; a1[j]=0.f; }
    for (int c=0;c<chunk;c++){
      float wgt = exp2f((float)(chunk-1-c)*d64l2);
      const float* ps = Pb + ((size_t)(bh*NCHUNK + c))*4096;
      float4 p0 = *(const float4*)(ps + r*64 + c8);
      float4 p1 = *(const float4*)(ps + r*64 + c8 + 4);
      float4 p2 = *(const float4*)(ps + (r+32)*64 + c8);
      float4 p3 = *(const float4*)(ps + (r+32)*64 + c8 + 4);
      a0[0]+=wgt*p0.x; a0[1]+=wgt*p0.y; a0[2]+=wgt*p0.z; a0[3]+=wgt*p0.w;
      a0[4]+=wgt*p1.x; a0[5]+=wgt*p1.y; a0[6]+=wgt*p1.z; a0[7]+=wgt*p1.w;
      a1[0]+=wgt*p2.x; a1[1]+=wgt*p2.y; a1[2]+=wgt*p2.z; a1[3]+=wgt*p2.w;
      a1[4]+=wgt*p3.x; a1[5]+=wgt*p3.y; a1[6]+=wgt*p3.z; a1[7]+=wgt*p3.w;
    }
    #pragma unroll
    for (int j=0;j<8;j++){
      Sp[r*PQ + c8 + j]      = f2b(a0[j]);
      Sp[(r+32)*PQ + c8 + j] = f2b(a1[j]);
    }
  }
  // z_prev (row 64) and zero pad rows 65..79
  if (tid < 64){
    float z = 0.f;
    for (int c=0;c<chunk;c++)
      z += exp2f((float)(chunk-1-c)*d64l2) * zPb[(bh*NCHUNK + c)*64 + tid];
    Sp[64*PQ + tid] = f2b(z);
  }
  for (int i = tid; i < 15*PQ; i += 256) Sp[65*PQ + i] = 0;
  __syncthreads();

  f32x4 acc[5];
  #pragma unroll
  for (int et=0;et<5;et++) acc[et] = (f32x4){0.f,0.f,0.f,0.f};
  #pragma unroll
  for (int et=0;et<5;et++)
    #pragma unroll
    for (int ks=0;ks<2;ks++){
      short8 a = *(const short8*)(Qb + (w*16 + m16)*PQ + ks*32 + quad*8);
      short8 bb = *(const short8*)(Sp + (et*16 + m16)*PQ + ks*32 + quad*8);
      acc[et] = __builtin_amdgcn_mfma_f32_16x16x32_bf16(a, bb, acc[et], 0, 0, 0);
    }
  int trow = w*16 + quad*4;
  if (m16 == 0){
    #pragma unroll
    for (int r=0;r<4;r++){
      int tl = trow + r;
      float pw = exp2f((float)(tl+1)*l2d);
      float den = fmaxf(denb[bh*SEQ + chunk*64 + tl] + pw*acc[4][r], 1e-5f);
      den_sm[tl] = 1.f/den;
    }
  }
  __syncthreads();
  #pragma unroll
  for (int r=0;r<4;r++){
    int tl = trow + r;
    float pw = exp2f((float)(tl+1)*l2d);
    float invden = den_sm[tl];
    int rowg = b*SEQ + chunk*64 + tl;
    float ls = 0.f;
    #pragma unroll
    for (int et=0;et<4;et++){
      int e = et*16 + m16;
      float ov = (numb[base + (size_t)tl*64 + e] + pw*acc[et][r])*invden;
      attnb[(size_t)rowg*D_MODEL + h*64 + e] = f2b(ov);
      ls += ov*ov;
    }
    // reduce sumsq over the 16 lanes of this row-group, one atomic per row per block
    ls += __shfl_xor(ls, 1, 64); ls += __shfl_xor(ls, 2, 64);
    ls += __shfl_xor(ls, 4, 64); ls += __shfl_xor(ls, 8, 64);
    if (m16 == 0) atomicAdd(&sumsq[rowg], ls);
  }
}

extern "C" void kernel_launch(void* const* d_in, const int* in_sizes, int n_in,
                              void* d_out, int out_size, void* d_ws, size_t ws_size,
                              hipStream_t stream)
{
  (void)in_sizes; (void)n_in; (void)out_size; (void)ws_size;
  const float* x       = (const float*)d_in[0];
  const float* w_ln    = (const float*)d_in[1];
  const float* w_comp  = (const float*)d_in[2];
  const float* w_qkv   = (const float*)d_in[3];
  const float* w_reso  = (const float*)d_in[4];
  const float* w_qn    = (const float*)d_in[5];
  const float* w_kn    = (const float*)d_in[6];
  const float* hdec    = (const float*)d_in[7];
  const float* temp    = (const float*)d_in[8];
  const float* w_ogate = (const float*)d_in[9];
  const float* w_proj  = (const float*)d_in[10];
  const float* w_mn    = (const float*)d_in[11];
  float* ws = (float*)d_ws;
  float* out = (float*)d_out;

  // fp32 region (floats)
  const size_t o_cKV    = 0;
  const size_t o_cG     = o_cKV    + (size_t)NBH*SEQ;
  const size_t o_den    = o_cG     + (size_t)NBH*SEQ;
  const size_t o_P      = o_den    + (size_t)NBH*SEQ;          // 24*16*4096 ([e][d])
  const size_t o_zP     = o_P      + (size_t)NBH*NCHUNK*4096;
  const size_t o_sumsq  = o_zP     + (size_t)NBH*NCHUNK*64;    // 2048 floats
  const size_t o_numb   = o_sumsq  + (size_t)NROWS;
  const size_t o_end    = o_numb   + (size_t)NBH*SEQ*64;

  // bf16 region (ushorts)
  unsigned short* bws = (unsigned short*)(ws + o_end);
  const size_t u_xn     = 0;
  const size_t u_latent = u_xn     + (size_t)NROWS*D_MODEL;
  const size_t u_memn   = u_latent + (size_t)NROWS*LATD;       // bf16 attn (A of out-GEMM)
  const size_t u_q      = u_memn   + (size_t)NROWS*D_MODEL;
  const size_t u_k      = u_q      + (size_t)NBH*SEQ*64;
  const size_t u_v      = u_k      + (size_t)NBH*SEQ*64;
  const size_t u_gate   = u_v      + (size_t)NBH*SEQ*64;       // 2048*768
  const size_t u_wtc    = u_gate   + (size_t)NROWS*D_MODEL;
  const size_t u_wtq    = u_wtc    + (size_t)LATD*D_MODEL;     // 2432*512, wtg follows
  const size_t u_wtg    = u_wtq    + (size_t)2432*LATD;        // contiguous: fused BT rows 2432..3199
  const size_t u_wtp    = u_wtg    + (size_t)D_MODEL*LATD;     // w_proj^T with w_mn folded

  // 1. weight converts (w_mn folded into wtp) + rmsnorm(x) + sumsq zero
  k_prep<<<2688, 256, 0, stream>>>(x, w_ln, bws + u_xn,
      w_comp, w_qkv, w_reso, w_ogate, w_proj, w_mn,
      bws + u_wtc, bws + u_wtq, bws + u_wtg, bws + u_wtp, ws + o_sumsq);
  // 2. latent = silu(xn @ w_compress) -> bf16   (64x64 tiles, 256 blocks, pipelined)
  k_gemm64<<<256, 256, 0, stream>>>(bws + u_xn, bws + u_wtc,
      nullptr, bws + u_latent, nullptr, nullptr, NROWS, LATD, D_MODEL, 1, LATD/64);
  // 3. fused qkv+params+gate GEMM with feat + coef epilogue (400 blocks, pipelined)
  k_gemm_fused<<<400, 256, 0, stream>>>(bws + u_latent, bws + u_wtq,
      w_qn, w_kn, hdec, temp, bws + u_q, bws + u_k, bws + u_v,
      ws + o_cKV, ws + o_cG, bws + u_gate);
  // 4. intra-chunk (MFMA)
  k_intra<<<NBH*NCHUNK, 256, 0, stream>>>(bws + u_q, bws + u_k, bws + u_v,
      ws + o_cKV, ws + o_cG, hdec, ws + o_numb, ws + o_den, ws + o_P, ws + o_zP);
  // 5. cross-chunk combine + bf16 attn + row sumsq (384 blocks, swizzled)
  k_cross<<<NBH*NCHUNK, 256, 0, stream>>>(bws + u_q, ws + o_P, ws + o_zP,
      ws + o_numb, ws + o_den, hdec, bws + u_memn, ws + o_sumsq);
  // 6. out = rmsnorm-scale * (attn_bf16 @ wtp') * gate  (384 blocks, pipelined)
  k_gemm64<<<384, 256, 0, stream>>>(bws + u_memn, bws + u_wtp,
      out, nullptr, bws + u_gate, ws + o_sumsq, NROWS, D_MODEL, D_MODEL, 3, D_MODEL/64);
}

// Round 11
// 148.203 us; speedup vs baseline: 1.5256x; 1.0087x over previous
//
#include <hip/hip_runtime.h>
#include <hip/hip_bf16.h>
#include <math.h>

// Problem constants (B=2, L=1024, D=768, H=12, DH=64, LAT=512)
#define D_MODEL 768
#define NHEAD   12
#define LATD    512
#define BATCH   2
#define SEQ     1024
#define NROWS   (BATCH*SEQ)          // 2048
#define NCHUNK  (SEQ/64)             // 16
#define NBH     (BATCH*NHEAD)        // 24
#define NFUSE   3200                 // qkv 2304 + params pad 128 + gate 768
#define PQ      72                   // LDS ushort pitch (144 B rows, 16B-aligned frags)

using short8 = __attribute__((ext_vector_type(8))) short;
using f32x4  = __attribute__((ext_vector_type(4))) float;

__device__ __forceinline__ float sigf(float x){ return 1.f/(1.f+expf(-x)); }
__device__ __forceinline__ float decay_of(float hd){
  float d = 0.3f + 0.65f*sigf(hd);
  return fminf(fmaxf(d, 1e-5f), 0.999f);
}
__device__ __forceinline__ unsigned short f2b(float f){
  __hip_bfloat16 h = __float2bfloat16(f);
  return *reinterpret_cast<unsigned short*>(&h);
}
__device__ __forceinline__ float bf2f(unsigned short u){
  unsigned int x = ((unsigned int)u) << 16;
  return __uint_as_float(x);
}
__device__ __forceinline__ void async16(const unsigned short* g, unsigned short* l){
  __builtin_amdgcn_global_load_lds((const __attribute__((address_space(1))) void*)g,
                                   (__attribute__((address_space(3))) void*)l, 16, 0, 0);
}

// shared rmsnorm-row body (D=768), one block of 256 per row
__device__ __forceinline__ void rms_row(const float* __restrict__ xr,
    const float* __restrict__ w, unsigned short* __restrict__ yr,
    int tid, float* red)
{
  float v0 = xr[tid], v1 = xr[tid+256], v2 = xr[tid+512];
  float s = v0*v0 + v1*v1 + v2*v2;
  #pragma unroll
  for (int off=32; off; off>>=1) s += __shfl_xor(s, off, 64);
  if ((tid & 63) == 0) red[tid>>6] = s;
  __syncthreads();
  s = red[0]+red[1]+red[2]+red[3];
  float sc = rsqrtf(s*(1.f/(float)D_MODEL) + 1e-6f);
  yr[tid]     = f2b(v0*sc*w[tid]);
  yr[tid+256] = f2b(v1*sc*w[tid+256]);
  yr[tid+512] = f2b(v2*sc*w[tid+512]);
}

// ---------------- prep: weight converts + rmsnorm(x) + sumsq zero, ONE launch ------
__global__ __launch_bounds__(256) void k_prep(
    const float* __restrict__ x, const float* __restrict__ w_ln,
    unsigned short* __restrict__ xn,
    const float* __restrict__ wc, const float* __restrict__ wq,
    const float* __restrict__ wr, const float* __restrict__ wg,
    const float* __restrict__ wp, const float* __restrict__ w_mn,
    unsigned short* __restrict__ wtc, unsigned short* __restrict__ wtq,
    unsigned short* __restrict__ wtg, unsigned short* __restrict__ wtp,
    float* __restrict__ sumsq)
{
  __shared__ unsigned short tile[64][65];
  __shared__ float red[4];
  int blk = blockIdx.x, t = threadIdx.x;
  if (blk >= 640){
    int row = blk - 640;
    rms_row(x + (size_t)row*D_MODEL, w_ln, xn + (size_t)row*D_MODEL, t, red);
    return;
  }
  const float* W; unsigned short* WT; int K, N, bx, by;
  const float* kscale = nullptr;
  if (blk < 96){ W=wc; WT=wtc; K=768; N=512; bx=blk&7; by=blk>>3; }
  else if (blk < 384){ int i=blk-96;  W=wq; WT=wtq; K=512; N=2304; bx=i%36; by=i/36; }
  else if (blk < 480){ int i=blk-384; W=wg; WT=wtg; K=512; N=768;  bx=i%12; by=i/12; }
  else if (blk < 624){ int i=blk-480; W=wp; WT=wtp; K=768; N=768;  bx=i%12; by=i/12; kscale=w_mn; }
  else {
    // w_reso [512][48] -> wtq rows 2304..2431 (zero-pad 2352..2431); blk 624 zeroes sumsq
    int i = blk - 624;                    // 0..15
    if (i == 0){
      #pragma unroll
      for (int j=0;j<8;j++) sumsq[t + j*256] = 0.f;
    }
    #pragma unroll
    for (int j=0;j<16;j++){
      int e = i*4096 + t + j*256;         // 0..65535
      int n = 2304 + (e >> 9), k = e & 511;
      float v = (n < 2352) ? wr[(size_t)k*48 + (n-2304)] : 0.f;
      wtq[(size_t)n*512 + k] = f2b(v);
    }
    return;
  }
  int k0 = by*64, n0 = bx*64, cr = t >> 6, cc = t & 63;
  #pragma unroll
  for (int i=0;i<16;i++){
    int r = cr + i*4;
    float v = W[(size_t)(k0+r)*N + n0 + cc];
    if (kscale) v *= kscale[k0+r];
    tile[r][cc] = f2b(v);
  }
  __syncthreads();
  #pragma unroll
  for (int i=0;i<16;i++){
    int nn = cr + i*4;
    WT[(size_t)(n0+nn)*K + k0 + cc] = tile[cc][nn];
  }
}

// ---------------- 64x64-tile bf16 MFMA GEMM, double-buffered 2-phase pipeline ------
// act: 1 = silu (bf16 Cb); 3 = rmsnorm-scale (sums) * aux gate (fp32 Cf)
__global__ __launch_bounds__(256) void k_gemm64(const unsigned short* __restrict__ A,
    const unsigned short* __restrict__ BT, float* __restrict__ Cf,
    unsigned short* __restrict__ Cb, const unsigned short* __restrict__ auxb,
    const float* __restrict__ sums, int M, int N, int K, int act, int NX)
{
  __shared__ unsigned short As[2*64*64];   // double-buffered
  __shared__ unsigned short Bs[2*64*64];
  int tid = threadIdx.x;
  int w = tid >> 6, lane = tid & 63;
  int m16 = lane & 15, quad = lane >> 4;
  int bid = blockIdx.x, cpx = gridDim.x >> 3;
  int swz = (bid & 7)*cpx + (bid >> 3);
  int bx = swz % NX, by = swz / NX;
  int bm = by*64, bn = bx*64;

  f32x4 acc[4];
  #pragma unroll
  for (int nt=0;nt<4;nt++) acc[nt] = (f32x4){0.f,0.f,0.f,0.f};

  int nk = K >> 6;
  // prologue: stage tile 0 into buf 0
  #pragma unroll
  for (int i=0;i<2;i++){
    int g = (w*2 + i)*64 + lane;
    int m = g >> 3, c = (g & 7) ^ (m & 7);
    async16(A  + (size_t)(bm+m)*K + c*8, As + (w*2+i)*512);
    async16(BT + (size_t)(bn+m)*K + c*8, Bs + (w*2+i)*512);
  }
  __syncthreads();
  int cur = 0;
  for (int t = 0; t < nk; ++t){
    if (t+1 < nk){
      int kk = (t+1) << 6;
      int nb = cur ^ 1;
      #pragma unroll
      for (int i=0;i<2;i++){
        int g = (w*2 + i)*64 + lane;
        int m = g >> 3, c = (g & 7) ^ (m & 7);
        async16(A  + (size_t)(bm+m)*K + kk + c*8, As + nb*4096 + (w*2+i)*512);
        async16(BT + (size_t)(bn+m)*K + kk + c*8, Bs + nb*4096 + (w*2+i)*512);
      }
    }
    #pragma unroll
    for (int s=0;s<2;s++){
      int row = w*16 + m16;
      short8 af = *(const short8*)(As + cur*4096 + (row*8 + ((s*4 + quad) ^ (row & 7)))*8);
      #pragma unroll
      for (int nt=0;nt<4;nt++){
        int n = nt*16 + m16;
        short8 bf = *(const short8*)(Bs + cur*4096 + (n*8 + ((s*4 + quad) ^ (n & 7)))*8);
        acc[nt] = __builtin_amdgcn_mfma_f32_16x16x32_bf16(af, bf, acc[nt], 0, 0, 0);
      }
    }
    __syncthreads();
    cur ^= 1;
  }
  #pragma unroll
  for (int r=0;r<4;r++){
    int row = bm + w*16 + quad*4 + r;
    float rowsc = 1.f;
    if (act == 3) rowsc = rsqrtf(sums[row]*(1.f/(float)D_MODEL) + 1e-6f);
    #pragma unroll
    for (int nt=0;nt<4;nt++){
      int col = bn + nt*16 + m16;
      float v = acc[nt][r];
      if (act == 1) v = v/(1.f + __expf(-v));
      else if (act == 3) v = v*rowsc*bf2f(auxb[(size_t)row*N + col]);
      if (Cf) Cf[(size_t)row*N + col] = v;
      if (Cb) Cb[(size_t)row*N + col] = f2b(v);
    }
  }
}

// ---------------- fused GEMM: [qkv | params | gate] = latent @ BT (N=3200) ----------
// 8-wave (512-thread) blocks on the 128x128 tile: 4 row-groups x 2 col-groups,
// wave owns 32 rows x 64 cols (full heads per wave). Double-buffered pipeline.
// Epilogue does feat (rmsnorm+rope+elu+1) + coef; math identical to 4-wave version.
// Section boundaries (768/1536/2304/2432) are 128-aligned -> all 8 waves of a block
// take the same top-level epilogue branch (no divergent __syncthreads).
__global__ __launch_bounds__(512) void k_gemm_fused(const unsigned short* __restrict__ A,
    const unsigned short* __restrict__ BT, const float* __restrict__ w_qn,
    const float* __restrict__ w_kn, const float* __restrict__ hdec,
    const float* __restrict__ temp, unsigned short* __restrict__ qf,
    unsigned short* __restrict__ kf, unsigned short* __restrict__ vf,
    float* __restrict__ cKV, float* __restrict__ cG,
    unsigned short* __restrict__ gateb)
{
  __shared__ __align__(16) unsigned short SM[4*128*64];   // As[2] | Bs[2]; pf re-alias later
  unsigned short* As = SM;                 // [2][128*64]
  unsigned short* Bs = SM + 2*128*64;      // [2][128*64]
  const int K = LATD;
  int tid = threadIdx.x;
  int w = tid >> 6, lane = tid & 63;       // w in 0..7
  int wm = (w & 3)*32, wn = (w >> 2)*64;   // 4 row-groups x 2 col-groups
  int m16 = lane & 15, quad = lane >> 4;
  int bid = blockIdx.x;
  int swz = (bid & 7)*50 + (bid >> 3);   // 400 = 8*50, bijective
  int bx = swz >> 4, by = swz & 15;      // by fastest within an XCD chunk
  int bm = by*128, bn = bx*128;

  f32x4 acc[2][4];
  #pragma unroll
  for (int i=0;i<2;i++)
    #pragma unroll
    for (int j=0;j<4;j++) acc[i][j] = (f32x4){0.f,0.f,0.f,0.f};

  const int nk = K >> 6;                 // 8
  // prologue: stage tile 0 into buf 0 (512 threads: 2 chunks each per matrix)
  #pragma unroll
  for (int i=0;i<2;i++){
    int g = (w*2 + i)*64 + lane;
    int m = g >> 3, c = (g & 7) ^ (m & 7);
    async16(A  + (size_t)(bm+m)*K + c*8, As + (w*2+i)*512);
    async16(BT + (size_t)(bn+m)*K + c*8, Bs + (w*2+i)*512);
  }
  __syncthreads();
  int cur = 0;
  for (int t = 0; t < nk; ++t){
    if (t+1 < nk){
      int kk = (t+1) << 6;
      int nb = cur ^ 1;
      #pragma unroll
      for (int i=0;i<2;i++){
        int g = (w*2 + i)*64 + lane;
        int m = g >> 3, c = (g & 7) ^ (m & 7);
        async16(A  + (size_t)(bm+m)*K + kk + c*8, As + nb*8192 + (w*2+i)*512);
        async16(BT + (size_t)(bn+m)*K + kk + c*8, Bs + nb*8192 + (w*2+i)*512);
      }
    }
    #pragma unroll
    for (int s=0;s<2;s++){
      short8 af[2], bf[4];
      #pragma unroll
      for (int mt=0;mt<2;mt++){
        int m = wm + mt*16 + m16;
        int idx = m*8 + ((s*4 + quad) ^ (m & 7));
        af[mt] = *(const short8*)(As + cur*8192 + idx*8);
      }
      #pragma unroll
      for (int nt=0;nt<4;nt++){
        int n = wn + nt*16 + m16;
        int idx = n*8 + ((s*4 + quad) ^ (n & 7));
        bf[nt] = *(const short8*)(Bs + cur*8192 + idx*8);
      }
      #pragma unroll
      for (int mt=0;mt<2;mt++)
        #pragma unroll
        for (int nt=0;nt<4;nt++)
          acc[mt][nt] = __builtin_amdgcn_mfma_f32_16x16x32_bf16(af[mt], bf[nt], acc[mt][nt], 0, 0, 0);
    }
    __syncthreads();
    cur ^= 1;
  }

  int colbase = bn + wn;                // 64-aligned; wave owns cols [colbase, colbase+64)
  if (colbase < 2304){
    int sec = colbase >= 1536 ? 2 : (colbase >= 768 ? 1 : 0);   // 0=q 1=k 2=v
    int h = (colbase - sec*768) >> 6;
    if (sec == 2){
      #pragma unroll
      for (int mt=0;mt<2;mt++)
        #pragma unroll
        for (int r=0;r<4;r++){
          int row = bm + wm + mt*16 + quad*4 + r;
          int b = row >> 10, t = row & 1023;
          size_t ob = (((size_t)(b*NHEAD+h))*SEQ + t)*64;
          #pragma unroll
          for (int nt=0;nt<4;nt++)
            vf[ob + nt*16 + m16] = f2b(acc[mt][nt][r]);
        }
    } else {
      const float* wnp = sec ? w_kn : w_qn;
      unsigned short* of = sec ? kf : qf;
      float wv4[4];
      #pragma unroll
      for (int nt=0;nt<4;nt++) wv4[nt] = wnp[nt*16 + m16];
      float inv0 = exp2f(-(float)m16*(1.f/32.f)*13.28771237954945f);  // 10000^{-m16/32}
      float inv1 = inv0 * 0.01f;                                      // * 10000^{-16/32}
      #pragma unroll
      for (int mt=0;mt<2;mt++)
        #pragma unroll
        for (int r=0;r<4;r++){
          int row = bm + wm + mt*16 + quad*4 + r;
          int b = row >> 10, t = row & 1023;
          float s = 0.f;
          #pragma unroll
          for (int nt=0;nt<4;nt++) s += acc[mt][nt][r]*acc[mt][nt][r];
          s += __shfl_xor(s, 1, 64); s += __shfl_xor(s, 2, 64);
          s += __shfl_xor(s, 4, 64); s += __shfl_xor(s, 8, 64);
          float rs = rsqrtf(s*(1.f/64.f) + 1e-6f);
          float qv[4];
          #pragma unroll
          for (int nt=0;nt<4;nt++) qv[nt] = acc[mt][nt][r]*rs*wv4[nt];
          float s0,c0,s1,c1;
          __sincosf((float)t*inv0, &s0, &c0);
          __sincosf((float)t*inv1, &s1, &c1);
          size_t ob = (((size_t)(b*NHEAD+h))*SEQ + t)*64;
          #pragma unroll
          for (int nt=0;nt<4;nt++){
            float rot = (nt < 2) ? -qv[nt+2] : qv[nt-2];
            float cs = (nt & 1) ? c1 : c0, sn = (nt & 1) ? s1 : s0;
            float val = qv[nt]*cs + rot*sn;
            val = (val > 0.f) ? val + 1.f : __expf(val);
            of[ob + nt*16 + m16] = f2b(val);
          }
        }
    }
  } else if (colbase < 2432){
    // resonance params block: all 8 waves of this block land here -> block sync OK.
    // Waves with colbase==2304 (w>>2==0) hold param cols 0..63 (valid < 48).
    float* pf = (float*)SM;               // [128][49] fp32 = 25088 B
    if (colbase == 2304){
      #pragma unroll
      for (int mt=0;mt<2;mt++)
        #pragma unroll
        for (int r=0;r<4;r++){
          int rowl = wm + mt*16 + quad*4 + r;
          #pragma unroll
          for (int nt=0;nt<4;nt++){
            int p = nt*16 + m16;
            if (p < 48) pf[rowl*49 + p] = acc[mt][nt][r];
          }
        }
    }
    __syncthreads();
    float tv = temp[0];
    #pragma unroll
    for (int i=0;i<3;i++){
      int idx2 = tid + i*512;             // 0..1535 = 128 rows x 12 heads
      int rowl = idx2 / 12, h = idx2 - rowl*12;
      int row = bm + rowl, b = row >> 10, t = row & 1023;
      const float* pr = pf + rowl*49 + h*4;
      float sa = sigf(pr[0]);
      float sp = sigf(pr[1])*3.14159265358979323846f;
      float ca = sigf(pr[2]);
      float cp = sigf(pr[3])*3.14159265358979323846f;
      float z = sa*ca*cosf(sp - cp)*tv;
      float gate = fminf(fmaxf(sigf(z)*1.2f - 0.1f, 0.05f), 0.95f);
      float dd = decay_of(hdec[h]);
      float df = expf((float)(t+1)*logf(dd));
      float g = df/(df + 1e-8f);
      int ci = (b*NHEAD + h)*SEQ + t;
      cKV[ci] = g*gate*(1.f - dd);
      cG[ci]  = 1.f/gate;
    }
  } else {
    // out-gate: silu -> bf16
    #pragma unroll
    for (int mt=0;mt<2;mt++)
      #pragma unroll
      for (int r=0;r<4;r++){
        int row = bm + wm + mt*16 + quad*4 + r;
        #pragma unroll
        for (int nt=0;nt<4;nt++){
          int gc = colbase + nt*16 + m16 - 2432;
          float v = acc[mt][nt][r];
          v = v/(1.f + __expf(-v));
          gateb[(size_t)row*D_MODEL + gc] = f2b(v);
        }
      }
  }
}

// ---------------- intra-chunk: MFMA scores + num/den + P^T/zP ----------------
__global__ __launch_bounds__(256) void k_intra(const unsigned short* __restrict__ qf,
    const unsigned short* __restrict__ kf, const unsigned short* __restrict__ vf,
    const float* __restrict__ cKVb, const float* __restrict__ cGb,
    const float* __restrict__ hdec, float* __restrict__ numb,
    float* __restrict__ denb, float* __restrict__ Pb, float* __restrict__ zPb)
{
  __shared__ __align__(16) unsigned short Qb[64*PQ];   // Q_f  [t][k]
  __shared__ __align__(16) unsigned short Kb[64*PQ];   // K_f  [s][d]
  __shared__ __align__(16) unsigned short KtS[64*PQ];  // (K_f*cps)^T [d][s]
  __shared__ __align__(16) unsigned short Wb[64*PQ];   // Wn   [t][s]
  __shared__ __align__(16) unsigned short Vt[80*PQ];   // V^T  [e][s]; row64 = invgate; 65..79 = 0
  __shared__ float cn[64], cps[64];
  int bid = blockIdx.x;
  int chunk = bid & 15, bh = bid >> 4, h = bh % NHEAD;
  int tid = threadIdx.x, w = tid >> 6, lane = tid & 63;
  int m16 = lane & 15, quad = lane >> 4;
  size_t base = ((size_t)bh*SEQ + chunk*64)*64;
  float d = decay_of(hdec[h]);
  float l2d = log2f(d);

  if (tid < 64){
    float c = cKVb[bh*SEQ + chunk*64 + tid];
    float pw = exp2f((float)(63 - tid)*l2d);
    cn[tid] = c;
    cps[tid] = c*pw;
    Vt[64*PQ + tid] = f2b(cGb[bh*SEQ + chunk*64 + tid]);
  }
  for (int i = tid; i < 15*PQ; i += 256) Vt[65*PQ + i] = 0;
  __syncthreads();   // cps ready for KtS staging

  #pragma unroll
  for (int i=0;i<2;i++){
    int g = tid + i*256;
    int r = g >> 3, c8 = (g & 7)*8;
    *(short8*)(Qb + r*PQ + c8) = *(const short8*)(qf + base + r*64 + c8);
    *(short8*)(Kb + r*PQ + c8) = *(const short8*)(kf + base + r*64 + c8);
  }
  {
    int s = tid & 63;
    float cpss = cps[s];
    #pragma unroll
    for (int i=0;i<2;i++){
      int c8 = ((tid >> 6) + i*4)*8;
      short8 vv = *(const short8*)(vf + base + s*64 + c8);
      short8 kk = *(const short8*)(kf + base + s*64 + c8);
      #pragma unroll
      for (int j=0;j<8;j++){
        Vt[(c8+j)*PQ + s] = ((unsigned short*)&vv)[j];
        KtS[(c8+j)*PQ + s] = f2b(bf2f(((unsigned short*)&kk)[j])*cpss);
      }
    }
  }
  __syncthreads();

  int trow = w*16 + quad*4;
  for (int stile=0; stile<4; stile++){
    if (stile > w){
      #pragma unroll
      for (int r=0;r<4;r++) Wb[(trow+r)*PQ + stile*16 + m16] = 0;
      continue;
    }
    f32x4 acc = (f32x4){0.f,0.f,0.f,0.f};
    #pragma unroll
    for (int ks=0;ks<2;ks++){
      short8 a = *(const short8*)(Qb + (w*16 + m16)*PQ + ks*32 + quad*8);
      short8 b = *(const short8*)(Kb + (stile*16 + m16)*PQ + ks*32 + quad*8);
      acc = __builtin_amdgcn_mfma_f32_16x16x32_bf16(a, b, acc, 0, 0, 0);
    }
    int s = stile*16 + m16;
    float cns = cn[s];
    #pragma unroll
    for (int r=0;r<4;r++){
      int t = trow + r;
      float wv = 0.f;
      if (s <= t) wv = acc[r]*exp2f((float)(t-s)*l2d)*cns;
      Wb[t*PQ + s] = f2b(wv);
    }
  }
  __syncthreads();

  {
    f32x4 acc[5];
    #pragma unroll
    for (int et=0;et<5;et++) acc[et] = (f32x4){0.f,0.f,0.f,0.f};
    #pragma unroll
    for (int et=0;et<5;et++)
      #pragma unroll
      for (int ks=0;ks<2;ks++){
        short8 a = *(const short8*)(Wb + (w*16 + m16)*PQ + ks*32 + quad*8);
        short8 b = *(const short8*)(Vt + (et*16 + m16)*PQ + ks*32 + quad*8);
        acc[et] = __builtin_amdgcn_mfma_f32_16x16x32_bf16(a, b, acc[et], 0, 0, 0);
      }
    #pragma unroll
    for (int et=0;et<4;et++)
      #pragma unroll
      for (int r=0;r<4;r++)
        numb[base + (size_t)(trow+r)*64 + et*16 + m16] = acc[et][r];
    if (m16 == 0){
      #pragma unroll
      for (int r=0;r<4;r++)
        denb[bh*SEQ + chunk*64 + trow + r] = acc[4][r];
    }
  }
  {
    #pragma unroll
    for (int j=0;j<5;j++){
      int tIdx = w + 4*j;
      int et = tIdx >> 2, dt = tIdx & 3;
      f32x4 acc = (f32x4){0.f,0.f,0.f,0.f};
      #pragma unroll
      for (int ks=0;ks<2;ks++){
        short8 a = *(const short8*)(Vt  + (et*16 + m16)*PQ + ks*32 + quad*8);
        short8 b = *(const short8*)(KtS + (dt*16 + m16)*PQ + ks*32 + quad*8);
        acc = __builtin_amdgcn_mfma_f32_16x16x32_bf16(a, b, acc, 0, 0, 0);
      }
      if (et < 4){
        #pragma unroll
        for (int r=0;r<4;r++)
          Pb[(size_t)bid*4096 + (et*16 + quad*4 + r)*64 + dt*16 + m16] = acc[r];
      } else {
        if (quad == 0) zPb[bid*64 + dt*16 + m16] = acc[0];
      }
    }
  }
}

// ---------------- cross-chunk: prefix-combine + attention out (bf16) + row sumsq ----
__global__ __launch_bounds__(256) void k_cross(const unsigned short* __restrict__ qf,
    const float* __restrict__ Pb, const float* __restrict__ zPb,
    const float* __restrict__ numb, const float* __restrict__ denb,
    const float* __restrict__ hdec, unsigned short* __restrict__ attnb,
    float* __restrict__ sumsq)
{
  __shared__ __align__(16) unsigned short Qb[64*PQ];   // Q_f [t][k]
  __shared__ __align__(16) unsigned short Sp[80*PQ];   // S [e][d]; row64 = zprev; 65..79 = 0
  __shared__ float den_sm[64];
  int bid = blockIdx.x;
  int swz = (bid & 7)*48 + (bid >> 3);     // 384 = 8*48, bijective
  int chunk = swz & 15, bh = swz >> 4;
  int h = bh % NHEAD, b = bh / NHEAD;
  int tid = threadIdx.x, w = tid >> 6, lane = tid & 63;
  int m16 = lane & 15, quad = lane >> 4;
  size_t base = ((size_t)bh*SEQ + chunk*64)*64;
  float d = decay_of(hdec[h]);
  float l2d = log2f(d);
  float d64l2 = 64.f*l2d;

  // stage Q
  #pragma unroll
  for (int i=0;i<2;i++){
    int g = tid + i*256;
    int r = g >> 3, c8 = (g & 7)*8;
    *(short8*)(Qb + r*PQ + c8) = *(const short8*)(qf + base + r*64 + c8);
  }

  // prefix-combine P -> S_prev (each thread owns 16 of the 4096 elements)
  {
    int r = tid >> 3, c8 = (tid & 7)*8;    // rows r and r+32, cols c8..c8+7
    float a0[8], a1[8];
    #pragma unroll
    for (int j=0;j<8;j++){ a0[j]=0.f; a1[j]=0.f; }
    for (int c=0;c<chunk;c++){
      float wgt = exp2f((float)(chunk-1-c)*d64l2);
      const float* ps = Pb + ((size_t)(bh*NCHUNK + c))*4096;
      float4 p0 = *(const float4*)(ps + r*64 + c8);
      float4 p1 = *(const float4*)(ps + r*64 + c8 + 4);
      float4 p2 = *(const float4*)(ps + (r+32)*64 + c8);
      float4 p3 = *(const float4*)(ps + (r+32)*64 + c8 + 4);
      a0[0]+=wgt*p0.x; a0[1]+=wgt*p0.y; a0[2]+=wgt*p0.z; a0[3]+=wgt*p0.w;
      a0[4]+=wgt*p1.x; a0[5]+=wgt*p1.y; a0[6]+=wgt*p1.z; a0[7]+=wgt*p1.w;
      a1[0]+=wgt*p2.x; a1[1]+=wgt*p2.y; a1[2]+=wgt*p2.z; a1[3]+=wgt*p2.w;
      a1[4]+=wgt*p3.x; a1[5]+=wgt*p3.y; a1[6]+=wgt*p3.z; a1[7]+=wgt*p3.w;
    }
    #pragma unroll
    for (int j=0;j<8;j++){
      Sp[r*PQ + c8 + j]      = f2b(a0[j]);
      Sp[(r+32)*PQ + c8 + j] = f2b(a1[j]);
    }
  }
  // z_prev (row 64) and zero pad rows 65..79
  if (tid < 64){
    float z = 0.f;
    for (int c=0;c<chunk;c++)
      z += exp2f((float)(chunk-1-c)*d64l2) * zPb[(bh*NCHUNK + c)*64 + tid];
    Sp[64*PQ + tid] = f2b(z);
  }
  for (int i = tid; i < 15*PQ; i += 256) Sp[65*PQ + i] = 0;
  __syncthreads();

  f32x4 acc[5];
  #pragma unroll
  for (int et=0;et<5;et++) acc[et] = (f32x4){0.f,0.f,0.f,0.f};
  #pragma unroll
  for (int et=0;et<5;et++)
    #pragma unroll
    for (int ks=0;ks<2;ks++){
      short8 a = *(const short8*)(Qb + (w*16 + m16)*PQ + ks*32 + quad*8);
      short8 bb = *(const short8*)(Sp + (et*16 + m16)*PQ + ks*32 + quad*8);
      acc[et] = __builtin_amdgcn_mfma_f32_16x16x32_bf16(a, bb, acc[et], 0, 0, 0);
    }
  int trow = w*16 + quad*4;
  if (m16 == 0){
    #pragma unroll
    for (int r=0;r<4;r++){
      int tl = trow + r;
      float pw = exp2f((float)(tl+1)*l2d);
      float den = fmaxf(denb[bh*SEQ + chunk*64 + tl] + pw*acc[4][r], 1e-5f);
      den_sm[tl] = 1.f/den;
    }
  }
  __syncthreads();
  #pragma unroll
  for (int r=0;r<4;r++){
    int tl = trow + r;
    float pw = exp2f((float)(tl+1)*l2d);
    float invden = den_sm[tl];
    int rowg = b*SEQ + chunk*64 + tl;
    float ls = 0.f;
    #pragma unroll
    for (int et=0;et<4;et++){
      int e = et*16 + m16;
      float ov = (numb[base + (size_t)tl*64 + e] + pw*acc[et][r])*invden;
      attnb[(size_t)rowg*D_MODEL + h*64 + e] = f2b(ov);
      ls += ov*ov;
    }
    // reduce sumsq over the 16 lanes of this row-group, one atomic per row per block
    ls += __shfl_xor(ls, 1, 64); ls += __shfl_xor(ls, 2, 64);
    ls += __shfl_xor(ls, 4, 64); ls += __shfl_xor(ls, 8, 64);
    if (m16 == 0) atomicAdd(&sumsq[rowg], ls);
  }
}

extern "C" void kernel_launch(void* const* d_in, const int* in_sizes, int n_in,
                              void* d_out, int out_size, void* d_ws, size_t ws_size,
                              hipStream_t stream)
{
  (void)in_sizes; (void)n_in; (void)out_size; (void)ws_size;
  const float* x       = (const float*)d_in[0];
  const float* w_ln    = (const float*)d_in[1];
  const float* w_comp  = (const float*)d_in[2];
  const float* w_qkv   = (const float*)d_in[3];
  const float* w_reso  = (const float*)d_in[4];
  const float* w_qn    = (const float*)d_in[5];
  const float* w_kn    = (const float*)d_in[6];
  const float* hdec    = (const float*)d_in[7];
  const float* temp    = (const float*)d_in[8];
  const float* w_ogate = (const float*)d_in[9];
  const float* w_proj  = (const float*)d_in[10];
  const float* w_mn    = (const float*)d_in[11];
  float* ws = (float*)d_ws;
  float* out = (float*)d_out;

  // fp32 region (floats)
  const size_t o_cKV    = 0;
  const size_t o_cG     = o_cKV    + (size_t)NBH*SEQ;
  const size_t o_den    = o_cG     + (size_t)NBH*SEQ;
  const size_t o_P      = o_den    + (size_t)NBH*SEQ;          // 24*16*4096 ([e][d])
  const size_t o_zP     = o_P      + (size_t)NBH*NCHUNK*4096;
  const size_t o_sumsq  = o_zP     + (size_t)NBH*NCHUNK*64;    // 2048 floats
  const size_t o_numb   = o_sumsq  + (size_t)NROWS;
  const size_t o_end    = o_numb   + (size_t)NBH*SEQ*64;

  // bf16 region (ushorts)
  unsigned short* bws = (unsigned short*)(ws + o_end);
  const size_t u_xn     = 0;
  const size_t u_latent = u_xn     + (size_t)NROWS*D_MODEL;
  const size_t u_memn   = u_latent + (size_t)NROWS*LATD;       // bf16 attn (A of out-GEMM)
  const size_t u_q      = u_memn   + (size_t)NROWS*D_MODEL;
  const size_t u_k      = u_q      + (size_t)NBH*SEQ*64;
  const size_t u_v      = u_k      + (size_t)NBH*SEQ*64;
  const size_t u_gate   = u_v      + (size_t)NBH*SEQ*64;       // 2048*768
  const size_t u_wtc    = u_gate   + (size_t)NROWS*D_MODEL;
  const size_t u_wtq    = u_wtc    + (size_t)LATD*D_MODEL;     // 2432*512, wtg follows
  const size_t u_wtg    = u_wtq    + (size_t)2432*LATD;        // contiguous: fused BT rows 2432..3199
  const size_t u_wtp    = u_wtg    + (size_t)D_MODEL*LATD;     // w_proj^T with w_mn folded

  // 1. weight converts (w_mn folded into wtp) + rmsnorm(x) + sumsq zero
  k_prep<<<2688, 256, 0, stream>>>(x, w_ln, bws + u_xn,
      w_comp, w_qkv, w_reso, w_ogate, w_proj, w_mn,
      bws + u_wtc, bws + u_wtq, bws + u_wtg, bws + u_wtp, ws + o_sumsq);
  // 2. latent = silu(xn @ w_compress) -> bf16   (64x64 tiles, 256 blocks, pipelined)
  k_gemm64<<<256, 256, 0, stream>>>(bws + u_xn, bws + u_wtc,
      nullptr, bws + u_latent, nullptr, nullptr, NROWS, LATD, D_MODEL, 1, LATD/64);
  // 3. fused qkv+params+gate GEMM with feat + coef epilogue (400 blocks x 512 thr)
  k_gemm_fused<<<400, 512, 0, stream>>>(bws + u_latent, bws + u_wtq,
      w_qn, w_kn, hdec, temp, bws + u_q, bws + u_k, bws + u_v,
      ws + o_cKV, ws + o_cG, bws + u_gate);
  // 4. intra-chunk (MFMA)
  k_intra<<<NBH*NCHUNK, 256, 0, stream>>>(bws + u_q, bws + u_k, bws + u_v,
      ws + o_cKV, ws + o_cG, hdec, ws + o_numb, ws + o_den, ws + o_P, ws + o_zP);
  // 5. cross-chunk combine + bf16 attn + row sumsq (384 blocks, swizzled)
  k_cross<<<NBH*NCHUNK, 256, 0, stream>>>(bws + u_q, ws + o_P, ws + o_zP,
      ws + o_numb, ws + o_den, hdec, bws + u_memn, ws + o_sumsq);
  // 6. out = rmsnorm-scale * (attn_bf16 @ wtp') * gate  (384 blocks, pipelined)
  k_gemm64<<<384, 256, 0, stream>>>(bws + u_memn, bws + u_wtp,
      out, nullptr, bws + u_gate, ws + o_sumsq, NROWS, D_MODEL, D_MODEL, 3, D_MODEL/64);
}